// Round 2
// baseline (2591.511 us; speedup 1.0000x reference)
//
#include <hip/hip_runtime.h>

typedef unsigned short u16;
typedef short v8s __attribute__((ext_vector_type(8)));
typedef short v4s16 __attribute__((ext_vector_type(4)));
typedef float v4f __attribute__((ext_vector_type(4)));

__device__ __forceinline__ float bf2f(u16 u){
  union { float f; unsigned int i; } c; c.i = ((unsigned int)u) << 16; return c.f;
}
__device__ __forceinline__ u16 f2bf(float f){
  union { float f; unsigned int i; } c; c.f = f;
  unsigned int r = c.i + 0x7FFFu + ((c.i >> 16) & 1u);
  return (u16)(r >> 16);
}

// ---------------- fp32 -> bf16 conversion of all inputs (one launch) ------------
struct CvtArgs {
  const float* s[13];
  u16* d[13];
  int n[13];
  int bstart[14];
};
__global__ __launch_bounds__(256) void cvt_all(CvtArgs a) {
  int j = 0;
  #pragma unroll
  for (int i = 1; i < 13; i++) if ((int)blockIdx.x >= a.bstart[i]) j = i;
  const int lb = blockIdx.x - a.bstart[j];
  const long base = (long)lb * 1024 + threadIdx.x * 4;
  if (base < a.n[j]) {
    const float4 f = *(const float4*)&a.s[j][base];
    v4s16 o;
    o.x = (short)f2bf(f.x); o.y = (short)f2bf(f.y);
    o.z = (short)f2bf(f.z); o.w = (short)f2bf(f.w);
    *(v4s16*)&a.d[j][base] = o;
  }
}

// ---------------- batched GEMM: C[g][M,N] = A[g][M,K] @ W[g][N,K]^T + bias[g] ----
// bf16 in, fp32 accumulate, MFMA 16x16x32. Output bf16 (OUTF=false) or fp32.
template<int BM, int BN, bool OUTF>
__global__ __launch_bounds__(256) void gemm_nt(
    const u16* __restrict__ A, long aBatch, int lda,
    const u16* __restrict__ W, long wBatch,
    const u16* __restrict__ bias, long bBatch,
    void* __restrict__ Cp, long cBatch, int ldc,
    int K)
{
  constexpr int BK = 64, LDT = BK + 8;  // 144B rows: 16B-aligned, ~2-way banks (free, m136)
  A    += (long)blockIdx.z * aBatch;
  W    += (long)blockIdx.z * wBatch;
  bias += (long)blockIdx.z * bBatch;
  const int row0 = blockIdx.y * BM, col0 = blockIdx.x * BN;
  __shared__ __align__(16) u16 As[BM * LDT];
  __shared__ __align__(16) u16 Bs[BN * LDT];
  const int tid = threadIdx.x, wid = tid >> 6, lane = tid & 63;
  constexpr int FM = (BM/2)/16, FN = (BN/2)/16;
  const int wr = (wid >> 1) * (BM/2), wc = (wid & 1) * (BN/2);
  v4f acc[FM][FN] = {};
  const int lr = lane & 15, lk = (lane >> 4) * 8;
  for (int k0 = 0; k0 < K; k0 += BK) {
    #pragma unroll
    for (int c = tid; c < BM*BK/8; c += 256) {
      int r = c >> 3, cc = (c & 7) * 8;
      *(v8s*)&As[r*LDT + cc] = *(const v8s*)&A[(long)(row0 + r)*lda + k0 + cc];
    }
    #pragma unroll
    for (int c = tid; c < BN*BK/8; c += 256) {
      int r = c >> 3, cc = (c & 7) * 8;
      *(v8s*)&Bs[r*LDT + cc] = *(const v8s*)&W[(long)(col0 + r)*K + k0 + cc];
    }
    __syncthreads();
    #pragma unroll
    for (int ks = 0; ks < BK; ks += 32) {
      v8s af[FM], bfv[FN];
      #pragma unroll
      for (int i = 0; i < FM; i++) af[i]  = *(const v8s*)&As[(wr + i*16 + lr)*LDT + ks + lk];
      #pragma unroll
      for (int j = 0; j < FN; j++) bfv[j] = *(const v8s*)&Bs[(wc + j*16 + lr)*LDT + ks + lk];
      #pragma unroll
      for (int i = 0; i < FM; i++)
        #pragma unroll
        for (int j = 0; j < FN; j++)
          acc[i][j] = __builtin_amdgcn_mfma_f32_16x16x32_bf16(af[i], bfv[j], acc[i][j], 0, 0, 0);
    }
    __syncthreads();
  }
  const int lc = lane & 15, lq = (lane >> 4) * 4;
  u16*   Cb = (u16*)Cp   + (long)blockIdx.z * cBatch;
  float* Cf = (float*)Cp + (long)blockIdx.z * cBatch;
  #pragma unroll
  for (int i = 0; i < FM; i++)
    #pragma unroll
    for (int j = 0; j < FN; j++) {
      const int cidx = col0 + wc + j*16 + lc;
      const float bv = bf2f(bias[cidx]);
      #pragma unroll
      for (int q = 0; q < 4; q++) {
        const int r = row0 + wr + i*16 + lq + q;
        if (OUTF) Cf[(long)r*ldc + cidx] = acc[i][j][q] + bv;
        else      Cb[(long)r*ldc + cidx] = f2bf(acc[i][j][q] + bv);
      }
    }
}

// ---------------- RoPE on q,k + relayout to (B,H,T,D), copy v -------------------
__global__ __launch_bounds__(256) void rope_split_k(
    const u16* __restrict__ qkv, const u16* __restrict__ cosb, const u16* __restrict__ sinb,
    u16* __restrict__ qr, u16* __restrict__ kr, u16* __restrict__ vv)
{
  const int idx  = blockIdx.x * 4 + (threadIdx.x >> 6);   // (b,h,t) row, B*H*T total
  const int lane = threadIdx.x & 63;
  const int t = idx & 1023;
  const int h = (idx >> 10) & 15;
  const int b = idx >> 14;
  const u16* base = qkv + ((long)(b*1024 + t))*3072 + h*64;
  const int i = lane >> 1;
  const float c = bf2f(cosb[t*32 + i]), s = bf2f(sinb[t*32 + i]);
  const long ro = (long)idx * 64 + lane;
  float xe = bf2f(base[2*i]), xo = bf2f(base[2*i + 1]);
  qr[ro] = f2bf((lane & 1) ? xe*s + xo*c : xe*c - xo*s);
  xe = bf2f(base[1024 + 2*i]); xo = bf2f(base[1024 + 2*i + 1]);
  kr[ro] = f2bf((lane & 1) ? xe*s + xo*c : xe*c - xo*s);
  vv[ro] = base[2048 + lane];
}

// ---------------- vector flash attention (wave per query row, online softmax) ---
template<int D>
__global__ __launch_bounds__(256) void flash_attn(
    const u16* __restrict__ qb, const u16* __restrict__ kb,
    const u16* __restrict__ vb, u16* __restrict__ ob,
    float scale, int n1, int n2,
    long q0, long q1, long q2, int qs,
    long k0, long k1, long k2, int ks,
    long v0, long v1, long v2, int vs,
    long o0, long o1, long o2, int os)
{
  const int wid = threadIdx.x >> 6, lane = threadIdx.x & 63;
  const int t = blockIdx.x * 4 + wid;
  const int prob = blockIdx.y;
  const int p2 = prob % n2, p1 = (prob / n2) % n1, p0 = prob / (n2 * n1);
  const u16* q  = qb + p0*q0 + p1*q1 + p2*q2;
  const u16* kp = kb + p0*k0 + p1*k1 + p2*k2;
  const u16* vp = vb + p0*v0 + p1*v1 + p2*v2;
  u16* op = ob + p0*o0 + p1*o1 + p2*o2;
  __shared__ __align__(16) float qls[4][D];
  if (lane < D) qls[wid][lane] = bf2f(q[(long)t*qs + lane]) * scale;
  const float NEG = -1.0e30f;
  float m = NEG, l = 0.f, o = 0.f;
  for (int kc = 0; kc <= t; kc += 64) {
    const int nk = min(64, t + 1 - kc);
    float s = NEG;
    if (lane < nk) {
      const u16* kr = kp + (long)(kc + lane) * ks;
      s = 0.f;
      #pragma unroll
      for (int d = 0; d < D; d += 8) {
        v8s kv = *(const v8s*)&kr[d];
        #pragma unroll
        for (int j = 0; j < 8; j++) s += bf2f((u16)kv[j]) * qls[wid][d + j];
      }
    }
    float cm = s;
    #pragma unroll
    for (int off = 32; off; off >>= 1) cm = fmaxf(cm, __shfl_xor(cm, off));
    const float mnew = fmaxf(m, cm);
    const float alpha = __expf(m - mnew);       // first iter: exp(-1e30) = 0
    const float p = __expf(s - mnew);           // masked lanes: exp(-1e30) = 0
    float ps = p;
    #pragma unroll
    for (int off = 32; off; off >>= 1) ps += __shfl_xor(ps, off);
    l = l * alpha + ps;
    o *= alpha;
    if (D == 64) {
      const u16* vr = vp + (long)kc * vs + lane;
      for (int j = 0; j < nk; j++) o += __shfl(p, j) * bf2f(vr[(long)j * vs]);
    } else {
      const int d = lane & 15, g = lane >> 4;
      const int j0 = g * 16, j1 = min(nk, j0 + 16);
      for (int j = j0; j < j1; j++) o += __shfl(p, j) * bf2f(vp[(long)(kc + j)*vs + d]);
    }
    m = mnew;
  }
  if (D == 16) { o += __shfl_xor(o, 16); o += __shfl_xor(o, 32); }
  const float res = o / l;
  if (lane < D) op[(long)t*os + lane] = f2bf(res);
}

// ---------------- ctx = mean over T of final tiny-layer output ------------------
__global__ void ctx_mean_k(const u16* __restrict__ tb, float* __restrict__ ctx)
{
  const int hb = blockIdx.x;              // h*2+b
  const int h = hb >> 1, b = hb & 1;
  const u16* p = tb + (long)h*2048*64 + (long)b*1024*64 + threadIdx.x;
  float s = 0.f;
  for (int t = 0; t < 1024; t++) s += bf2f(p[(long)t*64]);
  ctx[hb*64 + threadIdx.x] = s * (1.0f/1024.0f);
}

// ---------------- A,B low-rank projections --------------------------------------
__global__ __launch_bounds__(256) void ab_proj_k(const float* __restrict__ ctx,
    const u16* __restrict__ toA, const u16* __restrict__ toB,
    float* __restrict__ Am, float* __restrict__ Bm)
{
  const int hb = blockIdx.x; const int h = hb >> 1;
  const float* c = ctx + hb * 64;
  for (int n = threadIdx.x; n < 512; n += 256) {
    const u16* wa = toA + ((long)h*512 + n) * 64;
    const u16* wb = toB + ((long)h*512 + n) * 64;
    float sa = 0.f, sb = 0.f;
    for (int i = 0; i < 64; i++) { sa += c[i]*bf2f(wa[i]); sb += c[i]*bf2f(wb[i]); }
    Am[hb*512 + n] = sa;   // n = d*8+r
    Bm[hb*512 + n] = sb;   // n = r*64+d
  }
}

// ---------------- v += SCALE * (v @ A) @ B  (rank-8, in place) ------------------
__global__ __launch_bounds__(256) void delta_v_k(
    u16* __restrict__ v, const float* __restrict__ Am, const float* __restrict__ Bm)
{
  const long idx = (long)blockIdx.x * blockDim.x + threadIdx.x;  // (b,h,t) row
  const int h = (int)((idx >> 10) & 15);
  const int b = (int)(idx >> 14);
  u16* row = v + idx * 64;
  const float* A = Am + (h*2 + b) * 512;
  const float* B = Bm + (h*2 + b) * 512;
  float tmp[8] = {};
  #pragma unroll 8
  for (int d = 0; d < 64; d++) {
    const float vd = bf2f(row[d]);
    #pragma unroll
    for (int r = 0; r < 8; r++) tmp[r] += vd * A[d*8 + r];
  }
  #pragma unroll 8
  for (int d = 0; d < 64; d++) {
    float s = 0.f;
    #pragma unroll
    for (int r = 0; r < 8; r++) s += tmp[r] * B[r*64 + d];
    row[d] = f2bf(bf2f(row[d]) + 2.0f * s);   // SCALE = 16/8 = 2
  }
}

extern "C" void kernel_launch(void* const* d_in, const int* in_sizes, int n_in,
                              void* d_out, int out_size, void* d_ws, size_t ws_size,
                              hipStream_t stream) {
  (void)in_sizes; (void)n_in; (void)out_size; (void)ws_size;
  float* out = (float*)d_out;

  char* ws = (char*)d_ws;
  size_t off = 0;
  auto alloc = [&](size_t bytes){ void* p = ws + off; off += (bytes + 255) & ~(size_t)255; return p; };

  // bf16 copies of the 13 fp32 inputs
  static const int ns[13] = {2097152, 32768, 32768, 3145728, 3072, 1048576, 1024,
                             393216, 6144, 131072, 2048, 524288, 524288};
  u16* bufs[13];
  for (int i = 0; i < 13; i++) bufs[i] = (u16*)alloc((size_t)ns[i] * 2);
  u16* xb    = bufs[0];
  u16* cosb  = bufs[1];
  u16* sinb  = bufs[2];
  u16* attnw = bufs[3];
  u16* attnb = bufs[4];
  u16* projw = bufs[5];
  u16* projb = bufs[6];
  u16* hinw  = bufs[7];
  u16* hinb  = bufs[8];
  u16* houtw = bufs[9];
  u16* houtb = bufs[10];
  u16* toAb  = bufs[11];
  u16* toBb  = bufs[12];

  // pipeline buffers
  u16* qkv  = (u16*)alloc(6291456ull*2);   // (B,T,3C)
  u16* q_r  = (u16*)alloc(2097152ull*2);   // (B,H,T,64)
  u16* k_r  = (u16*)alloc(2097152ull*2);
  u16* v    = (u16*)alloc(2097152ull*2);
  u16* tqkv = (u16*)alloc(6291456ull*2);   // (H, B*T, 192)
  u16* tatt = (u16*)alloc(2097152ull*2);   // (H, B*T, 64)
  u16* tb0  = (u16*)alloc(2097152ull*2);
  u16* tb1  = (u16*)alloc(2097152ull*2);
  u16* yat  = (u16*)alloc(2097152ull*2);   // (B,T,C)
  float* ctx  = (float*)alloc(2048*4);
  float* Amat = (float*)alloc(16384*4);
  float* Bmat = (float*)alloc(16384*4);

  // 0. convert all inputs fp32 -> bf16
  CvtArgs ca;
  int bacc = 0;
  for (int i = 0; i < 13; i++) {
    ca.s[i] = (const float*)d_in[i];
    ca.d[i] = bufs[i];
    ca.n[i] = ns[i];
    ca.bstart[i] = bacc;
    bacc += (ns[i] + 1023) / 1024;
  }
  ca.bstart[13] = bacc;
  cvt_all<<<dim3(bacc), 256, 0, stream>>>(ca);

  // 1. qkv = x @ c_attn_w^T + b          (2048 x 3072 x 1024)
  gemm_nt<128,128,false><<<dim3(24,16,1),256,0,stream>>>(xb,0,1024, attnw,0, attnb,0,
                                                         qkv,0,3072, 1024);
  // 2. rope + split to (B,H,T,64)
  rope_split_k<<<dim3(8192),256,0,stream>>>(qkv, cosb, sinb, q_r, k_r, v);

  // 3. tiny hyper-net: 2 MHA layers over 16 heads
  const u16* tin = xb; long tinBatch = 64; int tinLda = 1024;  // layer0: x strided per head
  u16* touts[2] = {tb0, tb1};
  for (int l = 0; l < 2; l++) {
    gemm_nt<128,64,false><<<dim3(3,16,16),256,0,stream>>>(tin, tinBatch, tinLda,
        hinw + (size_t)l*192*64, (long)2*192*64,
        hinb + (size_t)l*192,    (long)2*192,
        tqkv, (long)2048*192, 192, 64);
    flash_attn<16><<<dim3(256,128),256,0,stream>>>(tqkv, tqkv+64, tqkv+128, tatt,
        0.25f, 2, 4,
        (long)2048*192, (long)1024*192, 16L, 192,
        (long)2048*192, (long)1024*192, 16L, 192,
        (long)2048*192, (long)1024*192, 16L, 192,
        (long)2048*64,  (long)1024*64,  16L, 64);
    gemm_nt<128,64,false><<<dim3(1,16,16),256,0,stream>>>(tatt, (long)2048*64, 64,
        houtw + (size_t)l*64*64, (long)2*64*64,
        houtb + (size_t)l*64,    (long)2*64,
        touts[l], (long)2048*64, 64, 64);
    tin = touts[l]; tinBatch = (long)2048*64; tinLda = 64;
  }
  // 4. ctx mean, A/B projections, rank-8 V update
  ctx_mean_k<<<dim3(32),64,0,stream>>>(tb1, ctx);
  ab_proj_k<<<dim3(32),256,0,stream>>>(ctx, toAb, toBb, Amat, Bmat);
  delta_v_k<<<dim3(128),256,0,stream>>>(v, Amat, Bmat);

  // 5. main causal attention (32 problems, D=64), output into (B,T,C) bf16
  flash_attn<64><<<dim3(256,32),256,0,stream>>>(q_r, k_r, v, yat,
      0.125f, 16, 1,
      (long)16*1024*64, (long)1024*64, 0L, 64,
      (long)16*1024*64, (long)1024*64, 0L, 64,
      (long)16*1024*64, (long)1024*64, 0L, 64,
      (long)1024*1024,  64L,           0L, 1024);

  // 6. out = yat @ c_proj_w^T + b        (2048 x 1024 x 1024), fp32 out
  gemm_nt<128,128,true><<<dim3(8,16,1),256,0,stream>>>(yat,0,1024, projw,0, projb,0,
                                                       out,0,1024, 1024);
}

// Round 4
// 554.658 us; speedup vs baseline: 4.6723x; 4.6723x over previous
//
#include <hip/hip_runtime.h>

typedef unsigned short u16;
typedef short v8s __attribute__((ext_vector_type(8)));
typedef short v4s16 __attribute__((ext_vector_type(4)));
typedef float v4f __attribute__((ext_vector_type(4)));

__device__ __forceinline__ float bf2f(u16 u){
  union { float f; unsigned int i; } c; c.i = ((unsigned int)u) << 16; return c.f;
}
__device__ __forceinline__ u16 f2bf(float f){
  union { float f; unsigned int i; } c; c.f = f;
  unsigned int r = c.i + 0x7FFFu + ((c.i >> 16) & 1u);
  return (u16)(r >> 16);
}

// ---------------- fp32 -> bf16 conversion of all inputs (one launch) ------------
struct CvtArgs {
  const float* s[13];
  u16* d[13];
  int n[13];
  int bstart[14];
};
__global__ __launch_bounds__(256) void cvt_all(CvtArgs a) {
  int j = 0;
  #pragma unroll
  for (int i = 1; i < 13; i++) if ((int)blockIdx.x >= a.bstart[i]) j = i;
  const int lb = blockIdx.x - a.bstart[j];
  const long base = (long)lb * 1024 + threadIdx.x * 4;
  if (base < a.n[j]) {
    const float4 f = *(const float4*)&a.s[j][base];
    v4s16 o;
    o.x = (short)f2bf(f.x); o.y = (short)f2bf(f.y);
    o.z = (short)f2bf(f.z); o.w = (short)f2bf(f.w);
    *(v4s16*)&a.d[j][base] = o;
  }
}

// ---------------- batched GEMM: C[g][M,N] = A[g][M,K] @ W[g][N,K]^T + bias[g] ----
template<int BM, int BN, bool OUTF>
__global__ __launch_bounds__(256) void gemm_nt(
    const u16* __restrict__ A, long aBatch, int lda,
    const u16* __restrict__ W, long wBatch,
    const u16* __restrict__ bias, long bBatch,
    void* __restrict__ Cp, long cBatch, int ldc,
    int K)
{
  constexpr int BK = 64, LDT = BK + 8;
  A    += (long)blockIdx.z * aBatch;
  W    += (long)blockIdx.z * wBatch;
  bias += (long)blockIdx.z * bBatch;
  const int row0 = blockIdx.y * BM, col0 = blockIdx.x * BN;
  __shared__ __align__(16) u16 As[BM * LDT];
  __shared__ __align__(16) u16 Bs[BN * LDT];
  const int tid = threadIdx.x, wid = tid >> 6, lane = tid & 63;
  constexpr int FM = (BM/2)/16, FN = (BN/2)/16;
  const int wr = (wid >> 1) * (BM/2), wc = (wid & 1) * (BN/2);
  v4f acc[FM][FN] = {};
  const int lr = lane & 15, lk = (lane >> 4) * 8;
  for (int k0 = 0; k0 < K; k0 += BK) {
    for (int c = tid; c < BM*BK/8; c += 256) {
      int r = c >> 3, cc = (c & 7) * 8;
      *(v8s*)&As[r*LDT + cc] = *(const v8s*)&A[(long)(row0 + r)*lda + k0 + cc];
    }
    for (int c = tid; c < BN*BK/8; c += 256) {
      int r = c >> 3, cc = (c & 7) * 8;
      *(v8s*)&Bs[r*LDT + cc] = *(const v8s*)&W[(long)(col0 + r)*K + k0 + cc];
    }
    __syncthreads();
    #pragma unroll
    for (int ks = 0; ks < BK; ks += 32) {
      v8s af[FM], bfv[FN];
      #pragma unroll
      for (int i = 0; i < FM; i++) af[i]  = *(const v8s*)&As[(wr + i*16 + lr)*LDT + ks + lk];
      #pragma unroll
      for (int j = 0; j < FN; j++) bfv[j] = *(const v8s*)&Bs[(wc + j*16 + lr)*LDT + ks + lk];
      #pragma unroll
      for (int i = 0; i < FM; i++)
        #pragma unroll
        for (int j = 0; j < FN; j++)
          acc[i][j] = __builtin_amdgcn_mfma_f32_16x16x32_bf16(af[i], bfv[j], acc[i][j], 0, 0, 0);
    }
    __syncthreads();
  }
  const int lc = lane & 15, lq = (lane >> 4) * 4;
  u16*   Cb = (u16*)Cp   + (long)blockIdx.z * cBatch;
  float* Cf = (float*)Cp + (long)blockIdx.z * cBatch;
  #pragma unroll
  for (int i = 0; i < FM; i++)
    #pragma unroll
    for (int j = 0; j < FN; j++) {
      const int cidx = col0 + wc + j*16 + lc;
      const float bv = bf2f(bias[cidx]);
      #pragma unroll
      for (int q = 0; q < 4; q++) {
        const int r = row0 + wr + i*16 + lq + q;
        if (OUTF) Cf[(long)r*ldc + cidx] = acc[i][j][q] + bv;
        else      Cb[(long)r*ldc + cidx] = f2bf(acc[i][j][q] + bv);
      }
    }
}

// ---------------- RoPE on q,k + relayout to (B,H,T,D), copy v -------------------
__global__ __launch_bounds__(256) void rope_split_k(
    const u16* __restrict__ qkv, const u16* __restrict__ cosb, const u16* __restrict__ sinb,
    u16* __restrict__ qr, u16* __restrict__ kr, u16* __restrict__ vv)
{
  const int idx  = blockIdx.x * 4 + (threadIdx.x >> 6);
  const int lane = threadIdx.x & 63;
  const int t = idx & 1023;
  const int h = (idx >> 10) & 15;
  const int b = idx >> 14;
  const u16* base = qkv + ((long)(b*1024 + t))*3072 + h*64;
  const int i = lane >> 1;
  const float c = bf2f(cosb[t*32 + i]), s = bf2f(sinb[t*32 + i]);
  const long ro = (long)idx * 64 + lane;
  float xe = bf2f(base[2*i]), xo = bf2f(base[2*i + 1]);
  qr[ro] = f2bf((lane & 1) ? xe*s + xo*c : xe*c - xo*s);
  xe = bf2f(base[1024 + 2*i]); xo = bf2f(base[1024 + 2*i + 1]);
  kr[ro] = f2bf((lane & 1) ? xe*s + xo*c : xe*c - xo*s);
  vv[ro] = base[2048 + lane];
}

// ---------------- MFMA flash attention ------------------------------------------
// 4 waves/block, wave w owns 16 q-rows (block = 64 rows). K-chunks of 64 keys
// staged in LDS (zero-padded to d=32 for D=16); V staged transposed so PV
// B-frags are contiguous ds_read_b128. Online softmax is wave-parallel
// (each q-row lives in one 16-lane group -> shfl_xor 1/2/4/8 reduces).
// P relayout C-layout -> A-layout through per-wave LDS tile.
template<int D>
__global__ __launch_bounds__(256) void flash_mfma(
    const u16* __restrict__ qb, const u16* __restrict__ kb,
    const u16* __restrict__ vb, u16* __restrict__ ob,
    float scale, int n1, int n2,
    long q0, long q1, long q2, int qs,
    long k0, long k1, long k2, int ks,
    long v0, long v1, long v2, int vs,
    long o0, long o1, long o2, int os)
{
  constexpr int KBLK = 64;
  constexpr int KD2 = (D < 32) ? 32 : D;   // storage d-extent (zero-padded)
  constexpr int LDK = KD2 + 8;             // 16B-aligned row strides
  constexpr int LDV = KBLK + 8;
  constexpr int LDP = KBLK + 8;
  constexpr int KD  = KD2 / 32;            // QK mfma k-steps (1 or 2)
  constexpr int NSUB = D / 16;             // output col sub-tiles (1 or 4)
  __shared__ __align__(16) u16 Ks[KBLK * LDK];
  __shared__ __align__(16) u16 Vs[D * LDV];
  __shared__ __align__(16) u16 Ps[4][16 * LDP];

  const int tid = threadIdx.x, wid = tid >> 6, lane = tid & 63;
  const int lr = lane & 15, lg = lane >> 4;
  const int prob = blockIdx.y;
  const int p2 = prob % n2, p1 = (prob / n2) % n1, p0 = prob / (n2 * n1);
  const u16* qp = qb + p0*q0 + p1*q1 + p2*q2;
  const u16* kp = kb + p0*k0 + p1*k1 + p2*k2;
  const u16* vp = vb + p0*v0 + p1*v1 + p2*v2;
  u16* op = ob + p0*o0 + p1*o1 + p2*o2;
  const int q0row = blockIdx.x * 64;
  const int wq = q0row + wid * 16;         // wave's first q-row

  // Q fragments in registers: lane holds row lr, d-block lg*8 (+32 per kd)
  v8s qf[KD];
  #pragma unroll
  for (int kd = 0; kd < KD; kd++) {
    const int dof = kd*32 + lg*8;
    v8s val = {};
    if (dof < D) val = *(const v8s*)&qp[(long)(wq + lr)*qs + dof];
    qf[kd] = val;
  }

  v4f Of[NSUB] = {};
  float m_r[4], l_r[4];
  #pragma unroll
  for (int r = 0; r < 4; r++) { m_r[r] = -1.0e30f; l_r[r] = 0.f; }

  const int nchunk = blockIdx.x + 1;       // causal: keys up to q0row+63
  for (int c = 0; c < nchunk; c++) {
    const int kc = c * 64;
    // stage K tile [KBLK][KD2] (zero-pad d >= D)
    for (int i = tid; i < KBLK*KD2/8; i += 256) {
      const int key = i / (KD2/8), d8 = (i % (KD2/8)) * 8;
      v8s val = {};
      if (d8 < D) val = *(const v8s*)&kp[(long)(kc + key)*ks + d8];
      *(v8s*)&Ks[key*LDK + d8] = val;
    }
    // stage V transposed [D][KBLK]
    for (int i = tid; i < D*KBLK; i += 256) {
      const int key = i / D, d = i % D;
      Vs[d*LDV + key] = vp[(long)(kc + key)*vs + d];
    }
    __syncthreads();
    if (kc <= wq + 15) {                   // wave not fully masked
      // ---- S = Q @ K^T (C-layout: col=key=lr within sub, row=lg*4+reg) ----
      v4f sf[4];
      #pragma unroll
      for (int f = 0; f < 4; f++) {
        v4f s = {};
        #pragma unroll
        for (int kd = 0; kd < KD; kd++) {
          const v8s kf = *(const v8s*)&Ks[(f*16 + lr)*LDK + kd*32 + lg*8];
          s = __builtin_amdgcn_mfma_f32_16x16x32_bf16(qf[kd], kf, s, 0, 0, 0);
        }
        sf[f] = s;
      }
      // ---- online softmax (wave-parallel per 16-lane group) ----
      float pvv[4][4];
      #pragma unroll
      for (int r = 0; r < 4; r++) {
        const int qrow = wq + lg*4 + r;
        float svv[4], mx = -1.0e30f;
        #pragma unroll
        for (int f = 0; f < 4; f++) {
          float v = sf[f][r] * scale;
          v = (kc + f*16 + lr <= qrow) ? v : -1.0e30f;
          svv[f] = v; mx = fmaxf(mx, v);
        }
        #pragma unroll
        for (int off = 1; off < 16; off <<= 1) mx = fmaxf(mx, __shfl_xor(mx, off));
        const float mn = fmaxf(m_r[r], mx);
        const float al = __expf(m_r[r] - mn);
        m_r[r] = mn;
        float ps = 0.f;
        #pragma unroll
        for (int f = 0; f < 4; f++) { const float p = __expf(svv[f] - mn); pvv[r][f] = p; ps += p; }
        #pragma unroll
        for (int off = 1; off < 16; off <<= 1) ps += __shfl_xor(ps, off);
        l_r[r] = l_r[r]*al + ps;
        // rescale O accumulator entries for this q-row (reg r) only
        #pragma unroll
        for (int sub = 0; sub < NSUB; sub++) Of[sub][r] *= al;
      }
      // ---- P -> LDS (A-layout rows=q, cols=key), then PV mfma ----
      #pragma unroll
      for (int r = 0; r < 4; r++)
        #pragma unroll
        for (int f = 0; f < 4; f++)
          Ps[wid][(lg*4 + r)*LDP + f*16 + lr] = f2bf(pvv[r][f]);
      asm volatile("s_waitcnt lgkmcnt(0)" ::: "memory");   // cross-lane RAW in-wave
      __builtin_amdgcn_sched_barrier(0);
      #pragma unroll
      for (int kb = 0; kb < 2; kb++) {
        const v8s pa = *(const v8s*)&Ps[wid][lr*LDP + kb*32 + lg*8];
        #pragma unroll
        for (int sub = 0; sub < NSUB; sub++) {
          const v8s vf = *(const v8s*)&Vs[(sub*16 + lr)*LDV + kb*32 + lg*8];
          Of[sub] = __builtin_amdgcn_mfma_f32_16x16x32_bf16(pa, vf, Of[sub], 0, 0, 0);
        }
      }
    }
    __syncthreads();
  }
  // ---- normalize + write ----
  #pragma unroll
  for (int sub = 0; sub < NSUB; sub++)
    #pragma unroll
    for (int r = 0; r < 4; r++) {
      const int qrow = wq + lg*4 + r;
      op[(long)qrow*os + sub*16 + lr] = f2bf(Of[sub][r] / l_r[r]);
    }
}

// ---------------- ctx = mean over T of final tiny-layer output ------------------
__global__ void ctx_mean_k(const u16* __restrict__ tb, float* __restrict__ ctx)
{
  const int hb = blockIdx.x;              // h*2+b
  const int h = hb >> 1, b = hb & 1;
  const u16* p = tb + (long)h*2048*64 + (long)b*1024*64 + threadIdx.x;
  float s = 0.f;
  for (int t = 0; t < 1024; t++) s += bf2f(p[(long)t*64]);
  ctx[hb*64 + threadIdx.x] = s * (1.0f/1024.0f);
}

// ---------------- A,B low-rank projections --------------------------------------
__global__ __launch_bounds__(256) void ab_proj_k(const float* __restrict__ ctx,
    const u16* __restrict__ toA, const u16* __restrict__ toB,
    float* __restrict__ Am, float* __restrict__ Bm)
{
  const int hb = blockIdx.x; const int h = hb >> 1;
  const float* c = ctx + hb * 64;
  for (int n = threadIdx.x; n < 512; n += 256) {
    const u16* wa = toA + ((long)h*512 + n) * 64;
    const u16* wb = toB + ((long)h*512 + n) * 64;
    float sa = 0.f, sb = 0.f;
    for (int i = 0; i < 64; i++) { sa += c[i]*bf2f(wa[i]); sb += c[i]*bf2f(wb[i]); }
    Am[hb*512 + n] = sa;   // n = d*8+r
    Bm[hb*512 + n] = sb;   // n = r*64+d
  }
}

// ---------------- v += SCALE * (v @ A) @ B  (rank-8, in place) ------------------
__global__ __launch_bounds__(256) void delta_v_k(
    u16* __restrict__ v, const float* __restrict__ Am, const float* __restrict__ Bm)
{
  const long idx = (long)blockIdx.x * blockDim.x + threadIdx.x;
  const int h = (int)((idx >> 10) & 15);
  const int b = (int)(idx >> 14);
  u16* row = v + idx * 64;
  const float* A = Am + (h*2 + b) * 512;
  const float* B = Bm + (h*2 + b) * 512;
  float tmp[8] = {};
  #pragma unroll 8
  for (int d = 0; d < 64; d++) {
    const float vd = bf2f(row[d]);
    #pragma unroll
    for (int r = 0; r < 8; r++) tmp[r] += vd * A[d*8 + r];
  }
  #pragma unroll 8
  for (int d = 0; d < 64; d++) {
    float s = 0.f;
    #pragma unroll
    for (int r = 0; r < 8; r++) s += tmp[r] * B[r*64 + d];
    row[d] = f2bf(bf2f(row[d]) + 2.0f * s);   // SCALE = 16/8 = 2
  }
}

extern "C" void kernel_launch(void* const* d_in, const int* in_sizes, int n_in,
                              void* d_out, int out_size, void* d_ws, size_t ws_size,
                              hipStream_t stream) {
  (void)in_sizes; (void)n_in; (void)out_size; (void)ws_size;
  float* out = (float*)d_out;

  char* ws = (char*)d_ws;
  size_t off = 0;
  auto alloc = [&](size_t bytes){ void* p = ws + off; off += (bytes + 255) & ~(size_t)255; return p; };

  static const int ns[13] = {2097152, 32768, 32768, 3145728, 3072, 1048576, 1024,
                             393216, 6144, 131072, 2048, 524288, 524288};
  u16* bufs[13];
  for (int i = 0; i < 13; i++) bufs[i] = (u16*)alloc((size_t)ns[i] * 2);
  u16* xb    = bufs[0];
  u16* cosb  = bufs[1];
  u16* sinb  = bufs[2];
  u16* attnw = bufs[3];
  u16* attnb = bufs[4];
  u16* projw = bufs[5];
  u16* projb = bufs[6];
  u16* hinw  = bufs[7];
  u16* hinb  = bufs[8];
  u16* houtw = bufs[9];
  u16* houtb = bufs[10];
  u16* toAb  = bufs[11];
  u16* toBb  = bufs[12];

  u16* qkv  = (u16*)alloc(6291456ull*2);   // (B,T,3C)
  u16* q_r  = (u16*)alloc(2097152ull*2);   // (B,H,T,64)
  u16* k_r  = (u16*)alloc(2097152ull*2);
  u16* v    = (u16*)alloc(2097152ull*2);
  u16* tqkv = (u16*)alloc(6291456ull*2);   // (H, B*T, 192)
  u16* tatt = (u16*)alloc(2097152ull*2);   // (H, B*T, 64)
  u16* tb0  = (u16*)alloc(2097152ull*2);
  u16* tb1  = (u16*)alloc(2097152ull*2);
  u16* yat  = (u16*)alloc(2097152ull*2);   // (B,T,C)
  float* ctx  = (float*)alloc(2048*4);
  float* Amat = (float*)alloc(16384*4);
  float* Bmat = (float*)alloc(16384*4);

  // 0. convert all inputs fp32 -> bf16
  CvtArgs ca;
  int bacc = 0;
  for (int i = 0; i < 13; i++) {
    ca.s[i] = (const float*)d_in[i];
    ca.d[i] = bufs[i];
    ca.n[i] = ns[i];
    ca.bstart[i] = bacc;
    bacc += (ns[i] + 1023) / 1024;
  }
  ca.bstart[13] = bacc;
  cvt_all<<<dim3(bacc), 256, 0, stream>>>(ca);

  // 1. qkv = x @ c_attn_w^T + b          (2048 x 3072 x 1024)
  gemm_nt<128,128,false><<<dim3(24,16,1),256,0,stream>>>(xb,0,1024, attnw,0, attnb,0,
                                                         qkv,0,3072, 1024);
  // 2. rope + split to (B,H,T,64)
  rope_split_k<<<dim3(8192),256,0,stream>>>(qkv, cosb, sinb, q_r, k_r, v);

  // 3. tiny hyper-net: 2 MHA layers over 16 heads
  const u16* tin = xb; long tinBatch = 64; int tinLda = 1024;
  u16* touts[2] = {tb0, tb1};
  for (int l = 0; l < 2; l++) {
    gemm_nt<128,64,false><<<dim3(3,16,16),256,0,stream>>>(tin, tinBatch, tinLda,
        hinw + (size_t)l*192*64, (long)2*192*64,
        hinb + (size_t)l*192,    (long)2*192,
        tqkv, (long)2048*192, 192, 64);
    flash_mfma<16><<<dim3(16,128),256,0,stream>>>(tqkv, tqkv+64, tqkv+128, tatt,
        0.25f, 2, 4,
        (long)2048*192, (long)1024*192, 16L, 192,
        (long)2048*192, (long)1024*192, 16L, 192,
        (long)2048*192, (long)1024*192, 16L, 192,
        (long)2048*64,  (long)1024*64,  16L, 64);
    gemm_nt<128,64,false><<<dim3(1,16,16),256,0,stream>>>(tatt, (long)2048*64, 64,
        houtw + (size_t)l*64*64, (long)2*64*64,
        houtb + (size_t)l*64,    (long)2*64,
        touts[l], (long)2048*64, 64, 64);
    tin = touts[l]; tinBatch = (long)2048*64; tinLda = 64;
  }
  // 4. ctx mean, A/B projections, rank-8 V update
  ctx_mean_k<<<dim3(32),64,0,stream>>>(tb1, ctx);
  ab_proj_k<<<dim3(32),256,0,stream>>>(ctx, toAb, toBb, Amat, Bmat);
  delta_v_k<<<dim3(128),256,0,stream>>>(v, Amat, Bmat);

  // 5. main causal attention (32 problems, D=64)
  flash_mfma<64><<<dim3(16,32),256,0,stream>>>(q_r, k_r, v, yat,
      0.125f, 16, 1,
      (long)16*1024*64, (long)1024*64, 0L, 64,
      (long)16*1024*64, (long)1024*64, 0L, 64,
      (long)16*1024*64, (long)1024*64, 0L, 64,
      (long)1024*1024,  64L,           0L, 1024);

  // 6. out = yat @ c_proj_w^T + b        (2048 x 1024 x 1024), fp32 out
  gemm_nt<128,128,true><<<dim3(8,16,1),256,0,stream>>>(yat,0,1024, projw,0, projb,0,
                                                       out,0,1024, 1024);
}

// Round 5
// 440.011 us; speedup vs baseline: 5.8896x; 1.2606x over previous
//
#include <hip/hip_runtime.h>

typedef unsigned short u16;
typedef short v8s __attribute__((ext_vector_type(8)));
typedef short v4s16 __attribute__((ext_vector_type(4)));
typedef float v4f __attribute__((ext_vector_type(4)));

__device__ __forceinline__ float bf2f(u16 u){
  union { float f; unsigned int i; } c; c.i = ((unsigned int)u) << 16; return c.f;
}
__device__ __forceinline__ u16 f2bf(float f){
  union { float f; unsigned int i; } c; c.f = f;
  unsigned int r = c.i + 0x7FFFu + ((c.i >> 16) & 1u);
  return (u16)(r >> 16);
}

// ---------------- fp32 -> bf16 conversion of all inputs (one launch) ------------
struct CvtArgs {
  const float* s[13];
  u16* d[13];
  int n[13];
  int bstart[14];
};
__global__ __launch_bounds__(256) void cvt_all(CvtArgs a) {
  int j = 0;
  #pragma unroll
  for (int i = 1; i < 13; i++) if ((int)blockIdx.x >= a.bstart[i]) j = i;
  const int lb = blockIdx.x - a.bstart[j];
  const long base = (long)lb * 1024 + threadIdx.x * 4;
  if (base < a.n[j]) {
    const float4 f = *(const float4*)&a.s[j][base];
    v4s16 o;
    o.x = (short)f2bf(f.x); o.y = (short)f2bf(f.y);
    o.z = (short)f2bf(f.z); o.w = (short)f2bf(f.w);
    *(v4s16*)&a.d[j][base] = o;
  }
}

// ---------------- batched GEMM: C[g][M,N] = A[g][M,K] @ W[g][N,K]^T + bias[g] ----
template<int BM, int BN, bool OUTF>
__global__ __launch_bounds__(256) void gemm_nt(
    const u16* __restrict__ A, long aBatch, int lda,
    const u16* __restrict__ W, long wBatch,
    const u16* __restrict__ bias, long bBatch,
    void* __restrict__ Cp, long cBatch, int ldc,
    int K)
{
  constexpr int BK = 64, LDT = BK + 8;
  A    += (long)blockIdx.z * aBatch;
  W    += (long)blockIdx.z * wBatch;
  bias += (long)blockIdx.z * bBatch;
  const int row0 = blockIdx.y * BM, col0 = blockIdx.x * BN;
  __shared__ __align__(16) u16 As[BM * LDT];
  __shared__ __align__(16) u16 Bs[BN * LDT];
  const int tid = threadIdx.x, wid = tid >> 6, lane = tid & 63;
  constexpr int FM = (BM/2)/16, FN = (BN/2)/16;
  const int wr = (wid >> 1) * (BM/2), wc = (wid & 1) * (BN/2);
  v4f acc[FM][FN] = {};
  const int lr = lane & 15, lk = (lane >> 4) * 8;
  for (int k0 = 0; k0 < K; k0 += BK) {
    for (int c = tid; c < BM*BK/8; c += 256) {
      int r = c >> 3, cc = (c & 7) * 8;
      *(v8s*)&As[r*LDT + cc] = *(const v8s*)&A[(long)(row0 + r)*lda + k0 + cc];
    }
    for (int c = tid; c < BN*BK/8; c += 256) {
      int r = c >> 3, cc = (c & 7) * 8;
      *(v8s*)&Bs[r*LDT + cc] = *(const v8s*)&W[(long)(col0 + r)*K + k0 + cc];
    }
    __syncthreads();
    #pragma unroll
    for (int ks = 0; ks < BK; ks += 32) {
      v8s af[FM], bfv[FN];
      #pragma unroll
      for (int i = 0; i < FM; i++) af[i]  = *(const v8s*)&As[(wr + i*16 + lr)*LDT + ks + lk];
      #pragma unroll
      for (int j = 0; j < FN; j++) bfv[j] = *(const v8s*)&Bs[(wc + j*16 + lr)*LDT + ks + lk];
      #pragma unroll
      for (int i = 0; i < FM; i++)
        #pragma unroll
        for (int j = 0; j < FN; j++)
          acc[i][j] = __builtin_amdgcn_mfma_f32_16x16x32_bf16(af[i], bfv[j], acc[i][j], 0, 0, 0);
    }
    __syncthreads();
  }
  const int lc = lane & 15, lq = (lane >> 4) * 4;
  u16*   Cb = (u16*)Cp   + (long)blockIdx.z * cBatch;
  float* Cf = (float*)Cp + (long)blockIdx.z * cBatch;
  #pragma unroll
  for (int i = 0; i < FM; i++)
    #pragma unroll
    for (int j = 0; j < FN; j++) {
      const int cidx = col0 + wc + j*16 + lc;
      const float bv = bf2f(bias[cidx]);
      #pragma unroll
      for (int q = 0; q < 4; q++) {
        const int r = row0 + wr + i*16 + lq + q;
        if (OUTF) Cf[(long)r*ldc + cidx] = acc[i][j][q] + bv;
        else      Cb[(long)r*ldc + cidx] = f2bf(acc[i][j][q] + bv);
      }
    }
}

// ---------------- RoPE on q,k + relayout to (B,H,T,D), copy v -------------------
__global__ __launch_bounds__(256) void rope_split_k(
    const u16* __restrict__ qkv, const u16* __restrict__ cosb, const u16* __restrict__ sinb,
    u16* __restrict__ qr, u16* __restrict__ kr, u16* __restrict__ vv)
{
  const int idx  = blockIdx.x * 4 + (threadIdx.x >> 6);
  const int lane = threadIdx.x & 63;
  const int t = idx & 1023;
  const int h = (idx >> 10) & 15;
  const int b = idx >> 14;
  const u16* base = qkv + ((long)(b*1024 + t))*3072 + h*64;
  const int i = lane >> 1;
  const float c = bf2f(cosb[t*32 + i]), s = bf2f(sinb[t*32 + i]);
  const long ro = (long)idx * 64 + lane;
  float xe = bf2f(base[2*i]), xo = bf2f(base[2*i + 1]);
  qr[ro] = f2bf((lane & 1) ? xe*s + xo*c : xe*c - xo*s);
  xe = bf2f(base[1024 + 2*i]); xo = bf2f(base[1024 + 2*i + 1]);
  kr[ro] = f2bf((lane & 1) ? xe*s + xo*c : xe*c - xo*s);
  vv[ro] = base[2048 + lane];
}

// ---------------- MFMA flash attention v2 ----------------------------------------
// 512 threads / 8 waves. Paired q-tiles: block x owns 64-row tiles ta=x and
// tb=15-x (uniform 17 chunk-computes/block). Waves 0-3 -> tile a, waves 4-7 ->
// tile b; each wave owns 16 q-rows. Double-buffered K/V LDS (1 barrier/chunk);
// chunk c+1 global loads issue BEFORE chunk-c compute (T14 issue-early/
// write-late). Online softmax wave-parallel per 16-lane group. P relayout via
// per-wave LDS tile (in-wave ordered, lgkmcnt-guarded).
template<int D>
__global__ __launch_bounds__(512) void flash_mfma(
    const u16* __restrict__ qb, const u16* __restrict__ kb,
    const u16* __restrict__ vb, u16* __restrict__ ob,
    float scale, int n1, int n2,
    long q0, long q1, long q2, int qs,
    long k0, long k1, long k2, int ks,
    long v0, long v1, long v2, int vs,
    long o0, long o1, long o2, int os)
{
  constexpr int KBLK = 64;
  constexpr int KD2 = (D < 32) ? 32 : D;   // storage d-extent (zero-padded)
  constexpr int LDK = KD2 + 8;
  constexpr int LDV = KBLK + 8;
  constexpr int LDP = KBLK + 8;
  constexpr int KD  = KD2 / 32;            // QK mfma k-steps (1 or 2)
  constexpr int NSUB = D / 16;             // output col sub-tiles (1 or 4)
  constexpr int KCH = KBLK * (KD2/8);      // K-tile v8s chunks (256 or 512)
  constexpr int VCH = (D/8) * KBLK;        // V-tile v8s chunks (128 or 512)
  __shared__ __align__(16) u16 Ks[2][KBLK * LDK];
  __shared__ __align__(16) u16 Vs[2][D * LDV];
  __shared__ __align__(16) u16 Ps[8][16 * LDP];

  const int tid = threadIdx.x, wid = tid >> 6, lane = tid & 63;
  const int lr = lane & 15, lg = lane >> 4;
  const int prob = blockIdx.y;
  const int p2 = prob % n2, p1 = (prob / n2) % n1, p0 = prob / (n2 * n1);
  const u16* qp = qb + p0*q0 + p1*q1 + p2*q2;
  const u16* kp = kb + p0*k0 + p1*k1 + p2*k2;
  const u16* vp = vb + p0*v0 + p1*v1 + p2*v2;
  u16* op = ob + p0*o0 + p1*o1 + p2*o2;

  const int ta = blockIdx.x;               // 0..7
  const int tb = 15 - ta;                  // 8..15
  const int wtile = (wid & 4) ? tb : ta;   // this wave's q-tile
  const int wq = wtile * 64 + (wid & 3) * 16;

  // Q fragments in registers: lane holds row lr, d-block lg*8 (+32 per kd)
  v8s qf[KD];
  #pragma unroll
  for (int kd = 0; kd < KD; kd++) {
    const int dof = kd*32 + lg*8;
    v8s val = {};
    if (dof < D) val = *(const v8s*)&qp[(long)(wq + lr)*qs + dof];
    qf[kd] = val;
  }

  v4f Of[NSUB] = {};
  float m_r[4], l_r[4];
  #pragma unroll
  for (int r = 0; r < 4; r++) { m_r[r] = -1.0e30f; l_r[r] = 0.f; }

  // staging thread->element maps (coalesced global reads)
  const int kkey = tid / (KD2/8), kd8 = (tid % (KD2/8)) * 8;
  const int vkey = tid / (D/8),  vd8 = (tid % (D/8)) * 8;
  v8s kreg = {}, vreg = {};

  // prologue: stage chunk 0 into buffer 0
  if (tid < KCH) { v8s t = {}; if (kd8 < D) t = *(const v8s*)&kp[(long)kkey*ks + kd8]; kreg = t; }
  if (tid < VCH) vreg = *(const v8s*)&vp[(long)vkey*vs + vd8];
  if (tid < KCH) *(v8s*)&Ks[0][kkey*LDK + kd8] = kreg;
  if (tid < VCH) {
    #pragma unroll
    for (int j = 0; j < 8; j++) Vs[0][(vd8+j)*LDV + vkey] = vreg[j];
  }
  __syncthreads();

  for (int c = 0; c <= tb; c++) {
    const int cur = c & 1, nxt = cur ^ 1;
    // issue next chunk's global loads early (latency hides under compute)
    if (c < tb) {
      const int kc2 = (c + 1) * 64;
      if (tid < KCH) { v8s t = {}; if (kd8 < D) t = *(const v8s*)&kp[(long)(kc2+kkey)*ks + kd8]; kreg = t; }
      if (tid < VCH) vreg = *(const v8s*)&vp[(long)(kc2+vkey)*vs + vd8];
    }
    if (c <= wtile) {                      // wave active for its tile
      const int kc = c * 64;
      // ---- S = Q @ K^T (C-layout: col=key=lr within sub, row=lg*4+reg) ----
      v4f sf[4];
      #pragma unroll
      for (int f = 0; f < 4; f++) {
        v4f s = {};
        #pragma unroll
        for (int kd = 0; kd < KD; kd++) {
          const v8s kf = *(const v8s*)&Ks[cur][(f*16 + lr)*LDK + kd*32 + lg*8];
          s = __builtin_amdgcn_mfma_f32_16x16x32_bf16(qf[kd], kf, s, 0, 0, 0);
        }
        sf[f] = s;
      }
      // ---- online softmax (wave-parallel per 16-lane group) ----
      float pvv[4][4];
      #pragma unroll
      for (int r = 0; r < 4; r++) {
        const int qrow = wq + lg*4 + r;
        float svv[4], mx = -1.0e30f;
        #pragma unroll
        for (int f = 0; f < 4; f++) {
          float v = sf[f][r] * scale;
          v = (kc + f*16 + lr <= qrow) ? v : -1.0e30f;
          svv[f] = v; mx = fmaxf(mx, v);
        }
        #pragma unroll
        for (int off = 1; off < 16; off <<= 1) mx = fmaxf(mx, __shfl_xor(mx, off));
        const float mn = fmaxf(m_r[r], mx);
        const float al = __expf(m_r[r] - mn);
        m_r[r] = mn;
        float ps = 0.f;
        #pragma unroll
        for (int f = 0; f < 4; f++) { const float p = __expf(svv[f] - mn); pvv[r][f] = p; ps += p; }
        #pragma unroll
        for (int off = 1; off < 16; off <<= 1) ps += __shfl_xor(ps, off);
        l_r[r] = l_r[r]*al + ps;
        #pragma unroll
        for (int sub = 0; sub < NSUB; sub++) Of[sub][r] *= al;
      }
      // ---- P -> LDS (A-layout rows=q, cols=key), then PV mfma ----
      #pragma unroll
      for (int r = 0; r < 4; r++)
        #pragma unroll
        for (int f = 0; f < 4; f++)
          Ps[wid][(lg*4 + r)*LDP + f*16 + lr] = f2bf(pvv[r][f]);
      asm volatile("s_waitcnt lgkmcnt(0)" ::: "memory");   // cross-lane RAW in-wave
      __builtin_amdgcn_sched_barrier(0);
      #pragma unroll
      for (int kb2 = 0; kb2 < 2; kb2++) {
        const v8s pa = *(const v8s*)&Ps[wid][lr*LDP + kb2*32 + lg*8];
        #pragma unroll
        for (int sub = 0; sub < NSUB; sub++) {
          const v8s vf = *(const v8s*)&Vs[cur][(sub*16 + lr)*LDV + kb2*32 + lg*8];
          Of[sub] = __builtin_amdgcn_mfma_f32_16x16x32_bf16(pa, vf, Of[sub], 0, 0, 0);
        }
      }
    }
    // write next chunk into the other buffer (safe: last read of it finished
    // before the barrier that ended iteration c-1)
    if (c < tb) {
      if (tid < KCH) *(v8s*)&Ks[nxt][kkey*LDK + kd8] = kreg;
      if (tid < VCH) {
        #pragma unroll
        for (int j = 0; j < 8; j++) Vs[nxt][(vd8+j)*LDV + vkey] = vreg[j];
      }
    }
    __syncthreads();
  }
  // ---- normalize + write ----
  #pragma unroll
  for (int sub = 0; sub < NSUB; sub++)
    #pragma unroll
    for (int r = 0; r < 4; r++) {
      const int qrow = wq + lg*4 + r;
      op[(long)qrow*os + sub*16 + lr] = f2bf(Of[sub][r] / l_r[r]);
    }
}

// ---------------- ctx = mean over T of final tiny-layer output ------------------
__global__ void ctx_mean_k(const u16* __restrict__ tb, float* __restrict__ ctx)
{
  const int hb = blockIdx.x;              // h*2+b
  const int h = hb >> 1, b = hb & 1;
  const u16* p = tb + (long)h*2048*64 + (long)b*1024*64 + threadIdx.x;
  float s = 0.f;
  for (int t = 0; t < 1024; t++) s += bf2f(p[(long)t*64]);
  ctx[hb*64 + threadIdx.x] = s * (1.0f/1024.0f);
}

// ---------------- A,B low-rank projections --------------------------------------
__global__ __launch_bounds__(256) void ab_proj_k(const float* __restrict__ ctx,
    const u16* __restrict__ toA, const u16* __restrict__ toB,
    float* __restrict__ Am, float* __restrict__ Bm)
{
  const int hb = blockIdx.x; const int h = hb >> 1;
  const float* c = ctx + hb * 64;
  for (int n = threadIdx.x; n < 512; n += 256) {
    const u16* wa = toA + ((long)h*512 + n) * 64;
    const u16* wb = toB + ((long)h*512 + n) * 64;
    float sa = 0.f, sb = 0.f;
    for (int i = 0; i < 64; i++) { sa += c[i]*bf2f(wa[i]); sb += c[i]*bf2f(wb[i]); }
    Am[hb*512 + n] = sa;   // n = d*8+r
    Bm[hb*512 + n] = sb;   // n = r*64+d
  }
}

// ---------------- v += SCALE * (v @ A) @ B  (rank-8, in place) ------------------
__global__ __launch_bounds__(256) void delta_v_k(
    u16* __restrict__ v, const float* __restrict__ Am, const float* __restrict__ Bm)
{
  const long idx = (long)blockIdx.x * blockDim.x + threadIdx.x;
  const int h = (int)((idx >> 10) & 15);
  const int b = (int)(idx >> 14);
  u16* row = v + idx * 64;
  const float* A = Am + (h*2 + b) * 512;
  const float* B = Bm + (h*2 + b) * 512;
  float tmp[8] = {};
  #pragma unroll 8
  for (int d = 0; d < 64; d++) {
    const float vd = bf2f(row[d]);
    #pragma unroll
    for (int r = 0; r < 8; r++) tmp[r] += vd * A[d*8 + r];
  }
  #pragma unroll 8
  for (int d = 0; d < 64; d++) {
    float s = 0.f;
    #pragma unroll
    for (int r = 0; r < 8; r++) s += tmp[r] * B[r*64 + d];
    row[d] = f2bf(bf2f(row[d]) + 2.0f * s);   // SCALE = 16/8 = 2
  }
}

extern "C" void kernel_launch(void* const* d_in, const int* in_sizes, int n_in,
                              void* d_out, int out_size, void* d_ws, size_t ws_size,
                              hipStream_t stream) {
  (void)in_sizes; (void)n_in; (void)out_size; (void)ws_size;
  float* out = (float*)d_out;

  char* ws = (char*)d_ws;
  size_t off = 0;
  auto alloc = [&](size_t bytes){ void* p = ws + off; off += (bytes + 255) & ~(size_t)255; return p; };

  static const int ns[13] = {2097152, 32768, 32768, 3145728, 3072, 1048576, 1024,
                             393216, 6144, 131072, 2048, 524288, 524288};
  u16* bufs[13];
  for (int i = 0; i < 13; i++) bufs[i] = (u16*)alloc((size_t)ns[i] * 2);
  u16* xb    = bufs[0];
  u16* cosb  = bufs[1];
  u16* sinb  = bufs[2];
  u16* attnw = bufs[3];
  u16* attnb = bufs[4];
  u16* projw = bufs[5];
  u16* projb = bufs[6];
  u16* hinw  = bufs[7];
  u16* hinb  = bufs[8];
  u16* houtw = bufs[9];
  u16* houtb = bufs[10];
  u16* toAb  = bufs[11];
  u16* toBb  = bufs[12];

  u16* qkv  = (u16*)alloc(6291456ull*2);   // (B,T,3C)
  u16* q_r  = (u16*)alloc(2097152ull*2);   // (B,H,T,64)
  u16* k_r  = (u16*)alloc(2097152ull*2);
  u16* v    = (u16*)alloc(2097152ull*2);
  u16* tqkv = (u16*)alloc(6291456ull*2);   // (H, B*T, 192)
  u16* tatt = (u16*)alloc(2097152ull*2);   // (H, B*T, 64)
  u16* tb0  = (u16*)alloc(2097152ull*2);
  u16* tb1  = (u16*)alloc(2097152ull*2);
  u16* yat  = (u16*)alloc(2097152ull*2);   // (B,T,C)
  float* ctx  = (float*)alloc(2048*4);
  float* Amat = (float*)alloc(16384*4);
  float* Bmat = (float*)alloc(16384*4);

  // 0. convert all inputs fp32 -> bf16
  CvtArgs ca;
  int bacc = 0;
  for (int i = 0; i < 13; i++) {
    ca.s[i] = (const float*)d_in[i];
    ca.d[i] = bufs[i];
    ca.n[i] = ns[i];
    ca.bstart[i] = bacc;
    bacc += (ns[i] + 1023) / 1024;
  }
  ca.bstart[13] = bacc;
  cvt_all<<<dim3(bacc), 256, 0, stream>>>(ca);

  // 1. qkv = x @ c_attn_w^T + b          (2048 x 3072 x 1024)
  gemm_nt<128,128,false><<<dim3(24,16,1),256,0,stream>>>(xb,0,1024, attnw,0, attnb,0,
                                                         qkv,0,3072, 1024);
  // 2. rope + split to (B,H,T,64)
  rope_split_k<<<dim3(8192),256,0,stream>>>(qkv, cosb, sinb, q_r, k_r, v);

  // 3. tiny hyper-net: 2 MHA layers over 16 heads
  const u16* tin = xb; long tinBatch = 64; int tinLda = 1024;
  u16* touts[2] = {tb0, tb1};
  for (int l = 0; l < 2; l++) {
    gemm_nt<128,64,false><<<dim3(3,16,16),256,0,stream>>>(tin, tinBatch, tinLda,
        hinw + (size_t)l*192*64, (long)2*192*64,
        hinb + (size_t)l*192,    (long)2*192,
        tqkv, (long)2048*192, 192, 64);
    flash_mfma<16><<<dim3(8,128),512,0,stream>>>(tqkv, tqkv+64, tqkv+128, tatt,
        0.25f, 2, 4,
        (long)2048*192, (long)1024*192, 16L, 192,
        (long)2048*192, (long)1024*192, 16L, 192,
        (long)2048*192, (long)1024*192, 16L, 192,
        (long)2048*64,  (long)1024*64,  16L, 64);
    gemm_nt<128,64,false><<<dim3(1,16,16),256,0,stream>>>(tatt, (long)2048*64, 64,
        houtw + (size_t)l*64*64, (long)2*64*64,
        houtb + (size_t)l*64,    (long)2*64,
        touts[l], (long)2048*64, 64, 64);
    tin = touts[l]; tinBatch = (long)2048*64; tinLda = 64;
  }
  // 4. ctx mean, A/B projections, rank-8 V update
  ctx_mean_k<<<dim3(32),64,0,stream>>>(tb1, ctx);
  ab_proj_k<<<dim3(32),256,0,stream>>>(ctx, toAb, toBb, Amat, Bmat);
  delta_v_k<<<dim3(128),256,0,stream>>>(v, Amat, Bmat);

  // 5. main causal attention (32 problems, D=64)
  flash_mfma<64><<<dim3(8,32),512,0,stream>>>(q_r, k_r, v, yat,
      0.125f, 16, 1,
      (long)16*1024*64, (long)1024*64, 0L, 64,
      (long)16*1024*64, (long)1024*64, 0L, 64,
      (long)16*1024*64, (long)1024*64, 0L, 64,
      (long)1024*1024,  64L,           0L, 1024);

  // 6. out = yat @ c_proj_w^T + b        (2048 x 1024 x 1024), fp32 out
  gemm_nt<128,128,true><<<dim3(8,16,1),256,0,stream>>>(yat,0,1024, projw,0, projb,0,
                                                       out,0,1024, 1024);
}

// Round 6
// 366.452 us; speedup vs baseline: 7.0719x; 1.2007x over previous
//
#include <hip/hip_runtime.h>

typedef unsigned short u16;
typedef short v8s __attribute__((ext_vector_type(8)));
typedef short v4s16 __attribute__((ext_vector_type(4)));
typedef float v4f __attribute__((ext_vector_type(4)));

#if defined(__has_builtin)
#  if __has_builtin(__builtin_amdgcn_exp2f)
#    define EXP2F(x) __builtin_amdgcn_exp2f(x)
#  else
#    define EXP2F(x) exp2f(x)
#  endif
#else
#  define EXP2F(x) exp2f(x)
#endif

__device__ __forceinline__ float bf2f(u16 u){
  union { float f; unsigned int i; } c; c.i = ((unsigned int)u) << 16; return c.f;
}
__device__ __forceinline__ u16 f2bf(float f){
  union { float f; unsigned int i; } c; c.f = f;
  unsigned int r = c.i + 0x7FFFu + ((c.i >> 16) & 1u);
  return (u16)(r >> 16);
}
__device__ __forceinline__ unsigned int cvt_pk_bf16(float lo, float hi){
  unsigned int r;
  asm("v_cvt_pk_bf16_f32 %0, %1, %2" : "=v"(r) : "v"(lo), "v"(hi));
  return r;
}

// ---------------- fp32 -> bf16 conversion of all inputs (one launch) ------------
struct CvtArgs {
  const float* s[13];
  u16* d[13];
  int n[13];
  int bstart[14];
};
__global__ __launch_bounds__(256) void cvt_all(CvtArgs a) {
  int j = 0;
  #pragma unroll
  for (int i = 1; i < 13; i++) if ((int)blockIdx.x >= a.bstart[i]) j = i;
  const int lb = blockIdx.x - a.bstart[j];
  const long base = (long)lb * 1024 + threadIdx.x * 4;
  if (base < a.n[j]) {
    const float4 f = *(const float4*)&a.s[j][base];
    v4s16 o;
    o.x = (short)f2bf(f.x); o.y = (short)f2bf(f.y);
    o.z = (short)f2bf(f.z); o.w = (short)f2bf(f.w);
    *(v4s16*)&a.d[j][base] = o;
  }
}

// ---------------- batched GEMM: C[g][M,N] = A[g][M,K] @ W[g][N,K]^T + bias[g] ----
template<int BM, int BN, bool OUTF>
__global__ __launch_bounds__(256) void gemm_nt(
    const u16* __restrict__ A, long aBatch, int lda,
    const u16* __restrict__ W, long wBatch,
    const u16* __restrict__ bias, long bBatch,
    void* __restrict__ Cp, long cBatch, int ldc,
    int K)
{
  constexpr int BK = 64, LDT = BK + 8;
  A    += (long)blockIdx.z * aBatch;
  W    += (long)blockIdx.z * wBatch;
  bias += (long)blockIdx.z * bBatch;
  const int row0 = blockIdx.y * BM, col0 = blockIdx.x * BN;
  __shared__ __align__(16) u16 As[BM * LDT];
  __shared__ __align__(16) u16 Bs[BN * LDT];
  const int tid = threadIdx.x, wid = tid >> 6, lane = tid & 63;
  constexpr int FM = (BM/2)/16, FN = (BN/2)/16;
  const int wr = (wid >> 1) * (BM/2), wc = (wid & 1) * (BN/2);
  v4f acc[FM][FN] = {};
  const int lr = lane & 15, lk = (lane >> 4) * 8;
  for (int k0 = 0; k0 < K; k0 += BK) {
    for (int c = tid; c < BM*BK/8; c += 256) {
      int r = c >> 3, cc = (c & 7) * 8;
      *(v8s*)&As[r*LDT + cc] = *(const v8s*)&A[(long)(row0 + r)*lda + k0 + cc];
    }
    for (int c = tid; c < BN*BK/8; c += 256) {
      int r = c >> 3, cc = (c & 7) * 8;
      *(v8s*)&Bs[r*LDT + cc] = *(const v8s*)&W[(long)(col0 + r)*K + k0 + cc];
    }
    __syncthreads();
    #pragma unroll
    for (int ks = 0; ks < BK; ks += 32) {
      v8s af[FM], bfv[FN];
      #pragma unroll
      for (int i = 0; i < FM; i++) af[i]  = *(const v8s*)&As[(wr + i*16 + lr)*LDT + ks + lk];
      #pragma unroll
      for (int j = 0; j < FN; j++) bfv[j] = *(const v8s*)&Bs[(wc + j*16 + lr)*LDT + ks + lk];
      #pragma unroll
      for (int i = 0; i < FM; i++)
        #pragma unroll
        for (int j = 0; j < FN; j++)
          acc[i][j] = __builtin_amdgcn_mfma_f32_16x16x32_bf16(af[i], bfv[j], acc[i][j], 0, 0, 0);
    }
    __syncthreads();
  }
  const int lc = lane & 15, lq = (lane >> 4) * 4;
  u16*   Cb = (u16*)Cp   + (long)blockIdx.z * cBatch;
  float* Cf = (float*)Cp + (long)blockIdx.z * cBatch;
  #pragma unroll
  for (int i = 0; i < FM; i++)
    #pragma unroll
    for (int j = 0; j < FN; j++) {
      const int cidx = col0 + wc + j*16 + lc;
      const float bv = bf2f(bias[cidx]);
      #pragma unroll
      for (int q = 0; q < 4; q++) {
        const int r = row0 + wr + i*16 + lq + q;
        if (OUTF) Cf[(long)r*ldc + cidx] = acc[i][j][q] + bv;
        else      Cb[(long)r*ldc + cidx] = f2bf(acc[i][j][q] + bv);
      }
    }
}

// ---------------- RoPE on q,k + relayout to (B,H,T,D), copy v -------------------
__global__ __launch_bounds__(256) void rope_split_k(
    const u16* __restrict__ qkv, const u16* __restrict__ cosb, const u16* __restrict__ sinb,
    u16* __restrict__ qr, u16* __restrict__ kr, u16* __restrict__ vv)
{
  const int idx  = blockIdx.x * 4 + (threadIdx.x >> 6);
  const int lane = threadIdx.x & 63;
  const int t = idx & 1023;
  const int h = (idx >> 10) & 15;
  const int b = idx >> 14;
  const u16* base = qkv + ((long)(b*1024 + t))*3072 + h*64;
  const int i = lane >> 1;
  const float c = bf2f(cosb[t*32 + i]), s = bf2f(sinb[t*32 + i]);
  const long ro = (long)idx * 64 + lane;
  float xe = bf2f(base[2*i]), xo = bf2f(base[2*i + 1]);
  qr[ro] = f2bf((lane & 1) ? xe*s + xo*c : xe*c - xo*s);
  xe = bf2f(base[1024 + 2*i]); xo = bf2f(base[1024 + 2*i + 1]);
  kr[ro] = f2bf((lane & 1) ? xe*s + xo*c : xe*c - xo*s);
  vv[ro] = base[2048 + lane];
}

// ---------------- MFMA flash attention v3 (swapped layout, in-reg softmax) -------
// 512 threads / 8 waves. Paired q-tiles: block (prob=x, ta=y) owns tiles ta and
// tb=15-ta. Waves 0-3 -> tile a, 4-7 -> tile b; each wave 16 q-rows.
// Swapped QK^T: S^T = mfma(K, Q) puts a full 16-key score slice per lane for
// q=lane&15 -> softmax is in-register (2 shfl_xor only). PV uses a k-dim
// permutation (key(lg,j)=16*(j>>2)+4lg+(j&3)) applied to BOTH operands so the
// P B-fragment is exactly the lane-resident exp values (zero shuffles, no P
// LDS). O^T accumulated (col=q), packed bf16 epilogue. Double-buffered K/V
// staging with issue-early/write-late (T14).
template<int D>
__global__ __launch_bounds__(512) void flash_mfma(
    const u16* __restrict__ qb, const u16* __restrict__ kb,
    const u16* __restrict__ vb, u16* __restrict__ ob,
    float scale, int n1, int n2,
    long q0, long q1, long q2, int qs,
    long k0, long k1, long k2, int ks,
    long v0, long v1, long v2, int vs,
    long o0, long o1, long o2, int os)
{
  constexpr int KBLK = 64;
  constexpr int KD2 = (D < 32) ? 32 : D;   // zero-padded d-extent
  constexpr int LDK = KD2 + 8;
  constexpr int LDV = KBLK + 8;
  constexpr int KD  = KD2 / 32;            // QK mfma k-steps
  constexpr int NSUB = D / 16;             // output d sub-tiles
  constexpr int KCH = KBLK * (KD2/8);
  constexpr int VCH = (D/8) * KBLK;
  __shared__ __align__(16) u16 Ks[2][KBLK * LDK];
  __shared__ __align__(16) u16 Vs[2][D * LDV];

  const int tid = threadIdx.x, wid = tid >> 6, lane = tid & 63;
  const int lr = lane & 15, lg = lane >> 4;
  const int prob = blockIdx.x;
  const int p2 = prob % n2, p1 = (prob / n2) % n1, p0 = prob / (n2 * n1);
  const u16* qp = qb + p0*q0 + p1*q1 + p2*q2;
  const u16* kp = kb + p0*k0 + p1*k1 + p2*k2;
  const u16* vp = vb + p0*v0 + p1*v1 + p2*v2;
  u16* op = ob + p0*o0 + p1*o1 + p2*o2;

  const int ta = blockIdx.y;               // 0..7
  const int tb = 15 - ta;                  // 8..15
  const int wtile = (wid & 4) ? tb : ta;
  const int wq = wtile * 64 + (wid & 3) * 16;
  const float scale2 = scale * 1.44269504f;   // fold log2(e): exp -> exp2

  // Q fragments (B-operand): lane holds q-row lr, dims lg*8 (+32 per kd)
  v8s qf[KD];
  #pragma unroll
  for (int kd = 0; kd < KD; kd++) {
    const int dof = kd*32 + lg*8;
    v8s val = {};
    if (dof < D) val = *(const v8s*)&qp[(long)(wq + lr)*qs + dof];
    qf[kd] = val;
  }

  v4f Of[NSUB] = {};                       // O^T: col=q=lr, row=d_local=4lg+reg
  float m2 = -1.0e30f, l = 0.f;            // per-lane (q=lr), log2 domain

  const int kkey = tid / (KD2/8), kd8 = (tid % (KD2/8)) * 8;
  const int vkey = tid / (D/8),  vd8 = (tid % (D/8)) * 8;
  v8s kreg = {}, vreg = {};

  // prologue: stage chunk 0 into buffer 0
  if (tid < KCH) { v8s t = {}; if (kd8 < D) t = *(const v8s*)&kp[(long)kkey*ks + kd8]; kreg = t; }
  if (tid < VCH) vreg = *(const v8s*)&vp[(long)vkey*vs + vd8];
  if (tid < KCH) *(v8s*)&Ks[0][kkey*LDK + kd8] = kreg;
  if (tid < VCH) {
    #pragma unroll
    for (int j = 0; j < 8; j++) Vs[0][(vd8+j)*LDV + vkey] = vreg[j];
  }
  __syncthreads();

  for (int c = 0; c <= tb; c++) {
    const int cur = c & 1, nxt = cur ^ 1;
    if (c < tb) {                          // issue next chunk loads early
      const int kc2 = (c + 1) * 64;
      if (tid < KCH) { v8s t = {}; if (kd8 < D) t = *(const v8s*)&kp[(long)(kc2+kkey)*ks + kd8]; kreg = t; }
      if (tid < VCH) vreg = *(const v8s*)&vp[(long)(kc2+vkey)*vs + vd8];
    }
    if (c <= wtile) {
      const int kc = c * 64;
      // ---- S^T = K @ Q^T : sf[f][r] = S[key=kc+16f+4lg+r][q=wq+lr] ----
      v4f sf[4];
      #pragma unroll
      for (int f = 0; f < 4; f++) {
        v4f s = {};
        #pragma unroll
        for (int kd = 0; kd < KD; kd++) {
          const v8s kf = *(const v8s*)&Ks[cur][(f*16 + lr)*LDK + kd*32 + lg*8];
          s = __builtin_amdgcn_mfma_f32_16x16x32_bf16(kf, qf[kd], s, 0, 0, 0);
        }
        sf[f] = s;
      }
      const int qg = wq + lr;
      if (kc + 63 > wq) {                  // diagonal region: apply causal mask
        #pragma unroll
        for (int f = 0; f < 4; f++)
          #pragma unroll
          for (int r = 0; r < 4; r++)
            sf[f][r] = (kc + 16*f + 4*lg + r <= qg) ? sf[f][r] : -3.0e38f;
      }
      // ---- in-register softmax over this lane's 16 keys + 2 shfl ----
      float mx0 = fmaxf(fmaxf(sf[0][0], sf[0][1]), fmaxf(sf[0][2], sf[0][3]));
      float mx1 = fmaxf(fmaxf(sf[1][0], sf[1][1]), fmaxf(sf[1][2], sf[1][3]));
      float mx2 = fmaxf(fmaxf(sf[2][0], sf[2][1]), fmaxf(sf[2][2], sf[2][3]));
      float mx3 = fmaxf(fmaxf(sf[3][0], sf[3][1]), fmaxf(sf[3][2], sf[3][3]));
      float mx = fmaxf(fmaxf(mx0, mx1), fmaxf(mx2, mx3));
      mx = fmaxf(mx, __shfl_xor(mx, 16));
      mx = fmaxf(mx, __shfl_xor(mx, 32));
      const float mn2 = fmaxf(m2, mx * scale2);
      const float al = EXP2F(m2 - mn2);
      m2 = mn2;
      float pv[4][4];
      #pragma unroll
      for (int f = 0; f < 4; f++)
        #pragma unroll
        for (int r = 0; r < 4; r++)
          pv[f][r] = EXP2F(__builtin_fmaf(sf[f][r], scale2, -mn2));
      float s0 = (pv[0][0]+pv[0][1]) + (pv[0][2]+pv[0][3]);
      float s1 = (pv[1][0]+pv[1][1]) + (pv[1][2]+pv[1][3]);
      float s2 = (pv[2][0]+pv[2][1]) + (pv[2][2]+pv[2][3]);
      float s3 = (pv[3][0]+pv[3][1]) + (pv[3][2]+pv[3][3]);
      float ps = (s0+s1) + (s2+s3);
      ps += __shfl_xor(ps, 16);
      ps += __shfl_xor(ps, 32);
      l = l * al + ps;
      #pragma unroll
      for (int sub = 0; sub < NSUB; sub++)
        #pragma unroll
        for (int r = 0; r < 4; r++) Of[sub][r] *= al;
      // ---- pack P to bf16 (lane-resident, zero shuffles) ----
      unsigned int pw[8];
      #pragma unroll
      for (int f = 0; f < 4; f++) {
        pw[2*f]   = cvt_pk_bf16(pv[f][0], pv[f][1]);
        pw[2*f+1] = cvt_pk_bf16(pv[f][2], pv[f][3]);
      }
      // ---- PV: O^T += V^T @ P^T with k-perm key(lg,j)=16*(j>>2)+4lg+(j&3) ----
      #pragma unroll
      for (int kb2 = 0; kb2 < 2; kb2++) {
        union { unsigned int w[4]; v8s v; } pb;
        pb.w[0] = pw[4*kb2];   pb.w[1] = pw[4*kb2+1];
        pb.w[2] = pw[4*kb2+2]; pb.w[3] = pw[4*kb2+3];
        #pragma unroll
        for (int sub = 0; sub < NSUB; sub++) {
          union { v4s16 h[2]; v8s v; } va;
          const int vbase = (sub*16 + lr)*LDV + kb2*32 + 4*lg;
          va.h[0] = *(const v4s16*)&Vs[cur][vbase];
          va.h[1] = *(const v4s16*)&Vs[cur][vbase + 16];
          Of[sub] = __builtin_amdgcn_mfma_f32_16x16x32_bf16(va.v, pb.v, Of[sub], 0, 0, 0);
        }
      }
    }
    if (c < tb) {                          // write next chunk (write-late)
      if (tid < KCH) *(v8s*)&Ks[nxt][kkey*LDK + kd8] = kreg;
      if (tid < VCH) {
        #pragma unroll
        for (int j = 0; j < 8; j++) Vs[nxt][(vd8+j)*LDV + vkey] = vreg[j];
      }
    }
    __syncthreads();
  }
  // ---- normalize + write: lane holds q=wq+lr, d = sub*16 + 4lg + r ----
  const float rl = __builtin_amdgcn_rcpf(l);
  #pragma unroll
  for (int sub = 0; sub < NSUB; sub++) {
    unsigned int w0 = cvt_pk_bf16(Of[sub][0]*rl, Of[sub][1]*rl);
    unsigned int w1 = cvt_pk_bf16(Of[sub][2]*rl, Of[sub][3]*rl);
    unsigned int* dst = (unsigned int*)&op[(long)(wq + lr)*os + sub*16 + 4*lg];
    dst[0] = w0; dst[1] = w1;
  }
}

// ---------------- ctx = mean over T of final tiny-layer output ------------------
__global__ void ctx_mean_k(const u16* __restrict__ tb, float* __restrict__ ctx)
{
  const int hb = blockIdx.x;              // h*2+b
  const int h = hb >> 1, b = hb & 1;
  const u16* p = tb + (long)h*2048*64 + (long)b*1024*64 + threadIdx.x;
  float s = 0.f;
  for (int t = 0; t < 1024; t++) s += bf2f(p[(long)t*64]);
  ctx[hb*64 + threadIdx.x] = s * (1.0f/1024.0f);
}

// ---------------- A,B low-rank projections --------------------------------------
__global__ __launch_bounds__(256) void ab_proj_k(const float* __restrict__ ctx,
    const u16* __restrict__ toA, const u16* __restrict__ toB,
    float* __restrict__ Am, float* __restrict__ Bm)
{
  const int hb = blockIdx.x; const int h = hb >> 1;
  const float* c = ctx + hb * 64;
  for (int n = threadIdx.x; n < 512; n += 256) {
    const u16* wa = toA + ((long)h*512 + n) * 64;
    const u16* wb = toB + ((long)h*512 + n) * 64;
    float sa = 0.f, sb = 0.f;
    for (int i = 0; i < 64; i++) { sa += c[i]*bf2f(wa[i]); sb += c[i]*bf2f(wb[i]); }
    Am[hb*512 + n] = sa;   // n = d*8+r
    Bm[hb*512 + n] = sb;   // n = r*64+d
  }
}

// ---------------- v += SCALE * (v @ A) @ B  (rank-8, in place) ------------------
__global__ __launch_bounds__(256) void delta_v_k(
    u16* __restrict__ v, const float* __restrict__ Am, const float* __restrict__ Bm)
{
  const long idx = (long)blockIdx.x * blockDim.x + threadIdx.x;
  const int h = (int)((idx >> 10) & 15);
  const int b = (int)(idx >> 14);
  u16* row = v + idx * 64;
  const float* A = Am + (h*2 + b) * 512;
  const float* B = Bm + (h*2 + b) * 512;
  float tmp[8] = {};
  #pragma unroll 8
  for (int d = 0; d < 64; d++) {
    const float vd = bf2f(row[d]);
    #pragma unroll
    for (int r = 0; r < 8; r++) tmp[r] += vd * A[d*8 + r];
  }
  #pragma unroll 8
  for (int d = 0; d < 64; d++) {
    float s = 0.f;
    #pragma unroll
    for (int r = 0; r < 8; r++) s += tmp[r] * B[r*64 + d];
    row[d] = f2bf(bf2f(row[d]) + 2.0f * s);   // SCALE = 16/8 = 2
  }
}

extern "C" void kernel_launch(void* const* d_in, const int* in_sizes, int n_in,
                              void* d_out, int out_size, void* d_ws, size_t ws_size,
                              hipStream_t stream) {
  (void)in_sizes; (void)n_in; (void)out_size; (void)ws_size;
  float* out = (float*)d_out;

  char* ws = (char*)d_ws;
  size_t off = 0;
  auto alloc = [&](size_t bytes){ void* p = ws + off; off += (bytes + 255) & ~(size_t)255; return p; };

  static const int ns[13] = {2097152, 32768, 32768, 3145728, 3072, 1048576, 1024,
                             393216, 6144, 131072, 2048, 524288, 524288};
  u16* bufs[13];
  for (int i = 0; i < 13; i++) bufs[i] = (u16*)alloc((size_t)ns[i] * 2);
  u16* xb    = bufs[0];
  u16* cosb  = bufs[1];
  u16* sinb  = bufs[2];
  u16* attnw = bufs[3];
  u16* attnb = bufs[4];
  u16* projw = bufs[5];
  u16* projb = bufs[6];
  u16* hinw  = bufs[7];
  u16* hinb  = bufs[8];
  u16* houtw = bufs[9];
  u16* houtb = bufs[10];
  u16* toAb  = bufs[11];
  u16* toBb  = bufs[12];

  u16* qkv  = (u16*)alloc(6291456ull*2);   // (B,T,3C)
  u16* q_r  = (u16*)alloc(2097152ull*2);   // (B,H,T,64)
  u16* k_r  = (u16*)alloc(2097152ull*2);
  u16* v    = (u16*)alloc(2097152ull*2);
  u16* tqkv = (u16*)alloc(6291456ull*2);   // (H, B*T, 192)
  u16* tatt = (u16*)alloc(2097152ull*2);   // (H, B*T, 64)
  u16* tb0  = (u16*)alloc(2097152ull*2);
  u16* tb1  = (u16*)alloc(2097152ull*2);
  u16* yat  = (u16*)alloc(2097152ull*2);   // (B,T,C)
  float* ctx  = (float*)alloc(2048*4);
  float* Amat = (float*)alloc(16384*4);
  float* Bmat = (float*)alloc(16384*4);

  // 0. convert all inputs fp32 -> bf16
  CvtArgs ca;
  int bacc = 0;
  for (int i = 0; i < 13; i++) {
    ca.s[i] = (const float*)d_in[i];
    ca.d[i] = bufs[i];
    ca.n[i] = ns[i];
    ca.bstart[i] = bacc;
    bacc += (ns[i] + 1023) / 1024;
  }
  ca.bstart[13] = bacc;
  cvt_all<<<dim3(bacc), 256, 0, stream>>>(ca);

  // 1. qkv = x @ c_attn_w^T + b          (2048 x 3072 x 1024)
  gemm_nt<128,128,false><<<dim3(24,16,1),256,0,stream>>>(xb,0,1024, attnw,0, attnb,0,
                                                         qkv,0,3072, 1024);
  // 2. rope + split to (B,H,T,64)
  rope_split_k<<<dim3(8192),256,0,stream>>>(qkv, cosb, sinb, q_r, k_r, v);

  // 3. tiny hyper-net: 2 MHA layers over 16 heads
  const u16* tin = xb; long tinBatch = 64; int tinLda = 1024;
  u16* touts[2] = {tb0, tb1};
  for (int l = 0; l < 2; l++) {
    gemm_nt<128,64,false><<<dim3(3,16,16),256,0,stream>>>(tin, tinBatch, tinLda,
        hinw + (size_t)l*192*64, (long)2*192*64,
        hinb + (size_t)l*192,    (long)2*192,
        tqkv, (long)2048*192, 192, 64);
    flash_mfma<16><<<dim3(128,8),512,0,stream>>>(tqkv, tqkv+64, tqkv+128, tatt,
        0.25f, 2, 4,
        (long)2048*192, (long)1024*192, 16L, 192,
        (long)2048*192, (long)1024*192, 16L, 192,
        (long)2048*192, (long)1024*192, 16L, 192,
        (long)2048*64,  (long)1024*64,  16L, 64);
    gemm_nt<128,64,false><<<dim3(1,16,16),256,0,stream>>>(tatt, (long)2048*64, 64,
        houtw + (size_t)l*64*64, (long)2*64*64,
        houtb + (size_t)l*64,    (long)2*64,
        touts[l], (long)2048*64, 64, 64);
    tin = touts[l]; tinBatch = (long)2048*64; tinLda = 64;
  }
  // 4. ctx mean, A/B projections, rank-8 V update
  ctx_mean_k<<<dim3(32),64,0,stream>>>(tb1, ctx);
  ab_proj_k<<<dim3(32),256,0,stream>>>(ctx, toAb, toBb, Amat, Bmat);
  delta_v_k<<<dim3(128),256,0,stream>>>(v, Amat, Bmat);

  // 5. main causal attention (32 problems, D=64)
  flash_mfma<64><<<dim3(32,8),512,0,stream>>>(q_r, k_r, v, yat,
      0.125f, 16, 1,
      (long)16*1024*64, (long)1024*64, 0L, 64,
      (long)16*1024*64, (long)1024*64, 0L, 64,
      (long)16*1024*64, (long)1024*64, 0L, 64,
      (long)1024*1024,  64L,           0L, 1024);

  // 6. out = yat @ c_proj_w^T + b        (2048 x 1024 x 1024), fp32 out
  gemm_nt<128,128,true><<<dim3(8,16,1),256,0,stream>>>(yat,0,1024, projw,0, projb,0,
                                                       out,0,1024, 1024);
}

// Round 7
// 279.364 us; speedup vs baseline: 9.2765x; 1.3117x over previous
//
#include <hip/hip_runtime.h>

typedef unsigned short u16;
typedef short v8s __attribute__((ext_vector_type(8)));
typedef short v4s16 __attribute__((ext_vector_type(4)));
typedef float v4f __attribute__((ext_vector_type(4)));

#if defined(__has_builtin)
#  if __has_builtin(__builtin_amdgcn_exp2f)
#    define EXP2F(x) __builtin_amdgcn_exp2f(x)
#  else
#    define EXP2F(x) exp2f(x)
#  endif
#else
#  define EXP2F(x) exp2f(x)
#endif

__device__ __forceinline__ float bf2f(u16 u){
  union { float f; unsigned int i; } c; c.i = ((unsigned int)u) << 16; return c.f;
}
__device__ __forceinline__ u16 f2bf(float f){
  union { float f; unsigned int i; } c; c.f = f;
  unsigned int r = c.i + 0x7FFFu + ((c.i >> 16) & 1u);
  return (u16)(r >> 16);
}
__device__ __forceinline__ unsigned int cvt_pk_bf16(float lo, float hi){
  unsigned int r;
  asm("v_cvt_pk_bf16_f32 %0, %1, %2" : "=v"(r) : "v"(lo), "v"(hi));
  return r;
}

// ---------------- fp32 -> bf16 conversion of all inputs (one launch) ------------
struct CvtArgs {
  const float* s[13];
  u16* d[13];
  int n[13];
  int bstart[14];
};
__global__ __launch_bounds__(256) void cvt_all(CvtArgs a) {
  int j = 0;
  #pragma unroll
  for (int i = 1; i < 13; i++) if ((int)blockIdx.x >= a.bstart[i]) j = i;
  const int lb = blockIdx.x - a.bstart[j];
  const long base = (long)lb * 1024 + threadIdx.x * 4;
  if (base < a.n[j]) {
    const float4 f = *(const float4*)&a.s[j][base];
    v4s16 o;
    o.x = (short)f2bf(f.x); o.y = (short)f2bf(f.y);
    o.z = (short)f2bf(f.z); o.w = (short)f2bf(f.w);
    *(v4s16*)&a.d[j][base] = o;
  }
}

// ---------------- batched GEMM: C[g][M,N] = A[g][M,K] @ W[g][N,K]^T + bias[g] ----
// 2-phase prefetch: tile k+1 global loads issue into regs BEFORE computing
// tile k; reg->LDS writes after the compute barrier (issue-early/write-late).
template<int BM, int BN, bool OUTF>
__global__ __launch_bounds__(256) void gemm_nt(
    const u16* __restrict__ A, long aBatch, int lda,
    const u16* __restrict__ W, long wBatch,
    const u16* __restrict__ bias, long bBatch,
    void* __restrict__ Cp, long cBatch, int ldc,
    int K)
{
  constexpr int BK = 64, LDT = BK + 8;
  constexpr int AC = BM / 32;              // A v8s-chunks per thread
  constexpr int BC = BN / 32;              // B v8s-chunks per thread
  A    += (long)blockIdx.z * aBatch;
  W    += (long)blockIdx.z * wBatch;
  bias += (long)blockIdx.z * bBatch;
  const int row0 = blockIdx.y * BM, col0 = blockIdx.x * BN;
  __shared__ __align__(16) u16 As[BM * LDT];
  __shared__ __align__(16) u16 Bs[BN * LDT];
  const int tid = threadIdx.x, wid = tid >> 6, lane = tid & 63;
  constexpr int FM = (BM/2)/16, FN = (BN/2)/16;
  const int wr = (wid >> 1) * (BM/2), wc = (wid & 1) * (BN/2);
  v4f acc[FM][FN] = {};
  const int lr = lane & 15, lk = (lane >> 4) * 8;

  v8s areg[AC], breg[BC];
  auto loadAB = [&](int k0) {
    #pragma unroll
    for (int i = 0; i < AC; i++) {
      const int c = tid + i*256, r = c >> 3, cc = (c & 7) * 8;
      areg[i] = *(const v8s*)&A[(long)(row0 + r)*lda + k0 + cc];
    }
    #pragma unroll
    for (int i = 0; i < BC; i++) {
      const int c = tid + i*256, r = c >> 3, cc = (c & 7) * 8;
      breg[i] = *(const v8s*)&W[(long)(col0 + r)*K + k0 + cc];
    }
  };
  auto writeAB = [&]() {
    #pragma unroll
    for (int i = 0; i < AC; i++) {
      const int c = tid + i*256, r = c >> 3, cc = (c & 7) * 8;
      *(v8s*)&As[r*LDT + cc] = areg[i];
    }
    #pragma unroll
    for (int i = 0; i < BC; i++) {
      const int c = tid + i*256, r = c >> 3, cc = (c & 7) * 8;
      *(v8s*)&Bs[r*LDT + cc] = breg[i];
    }
  };

  loadAB(0); writeAB();
  __syncthreads();
  for (int k0 = 0; k0 < K; k0 += BK) {
    if (k0 + BK < K) loadAB(k0 + BK);      // issue next tile early
    #pragma unroll
    for (int ks = 0; ks < BK; ks += 32) {
      v8s af[FM], bfv[FN];
      #pragma unroll
      for (int i = 0; i < FM; i++) af[i]  = *(const v8s*)&As[(wr + i*16 + lr)*LDT + ks + lk];
      #pragma unroll
      for (int j = 0; j < FN; j++) bfv[j] = *(const v8s*)&Bs[(wc + j*16 + lr)*LDT + ks + lk];
      #pragma unroll
      for (int i = 0; i < FM; i++)
        #pragma unroll
        for (int j = 0; j < FN; j++)
          acc[i][j] = __builtin_amdgcn_mfma_f32_16x16x32_bf16(af[i], bfv[j], acc[i][j], 0, 0, 0);
    }
    __syncthreads();
    if (k0 + BK < K) {                     // write-late into same buffer
      writeAB();
      __syncthreads();
    }
  }
  const int lc = lane & 15, lq = (lane >> 4) * 4;
  u16*   Cb = (u16*)Cp   + (long)blockIdx.z * cBatch;
  float* Cf = (float*)Cp + (long)blockIdx.z * cBatch;
  #pragma unroll
  for (int i = 0; i < FM; i++)
    #pragma unroll
    for (int j = 0; j < FN; j++) {
      const int cidx = col0 + wc + j*16 + lc;
      const float bv = bf2f(bias[cidx]);
      #pragma unroll
      for (int q = 0; q < 4; q++) {
        const int r = row0 + wr + i*16 + lq + q;
        if (OUTF) Cf[(long)r*ldc + cidx] = acc[i][j][q] + bv;
        else      Cb[(long)r*ldc + cidx] = f2bf(acc[i][j][q] + bv);
      }
    }
}

// ---------------- RoPE on q,k + relayout to (B,H,T,D), copy v -------------------
__global__ __launch_bounds__(256) void rope_split_k(
    const u16* __restrict__ qkv, const u16* __restrict__ cosb, const u16* __restrict__ sinb,
    u16* __restrict__ qr, u16* __restrict__ kr, u16* __restrict__ vv)
{
  const int idx  = blockIdx.x * 4 + (threadIdx.x >> 6);
  const int lane = threadIdx.x & 63;
  const int t = idx & 1023;
  const int h = (idx >> 10) & 15;
  const int b = idx >> 14;
  const u16* base = qkv + ((long)(b*1024 + t))*3072 + h*64;
  const int i = lane >> 1;
  const float c = bf2f(cosb[t*32 + i]), s = bf2f(sinb[t*32 + i]);
  const long ro = (long)idx * 64 + lane;
  float xe = bf2f(base[2*i]), xo = bf2f(base[2*i + 1]);
  qr[ro] = f2bf((lane & 1) ? xe*s + xo*c : xe*c - xo*s);
  xe = bf2f(base[1024 + 2*i]); xo = bf2f(base[1024 + 2*i + 1]);
  kr[ro] = f2bf((lane & 1) ? xe*s + xo*c : xe*c - xo*s);
  vv[ro] = base[2048 + lane];
}

// ---------------- MFMA flash attention v3 (swapped layout, in-reg softmax) -------
template<int D>
__global__ __launch_bounds__(512) void flash_mfma(
    const u16* __restrict__ qb, const u16* __restrict__ kb,
    const u16* __restrict__ vb, u16* __restrict__ ob,
    float scale, int n1, int n2,
    long q0, long q1, long q2, int qs,
    long k0, long k1, long k2, int ks,
    long v0, long v1, long v2, int vs,
    long o0, long o1, long o2, int os)
{
  constexpr int KBLK = 64;
  constexpr int KD2 = (D < 32) ? 32 : D;
  constexpr int LDK = KD2 + 8;
  constexpr int LDV = KBLK + 8;
  constexpr int KD  = KD2 / 32;
  constexpr int NSUB = D / 16;
  constexpr int KCH = KBLK * (KD2/8);
  constexpr int VCH = (D/8) * KBLK;
  __shared__ __align__(16) u16 Ks[2][KBLK * LDK];
  __shared__ __align__(16) u16 Vs[2][D * LDV];

  const int tid = threadIdx.x, wid = tid >> 6, lane = tid & 63;
  const int lr = lane & 15, lg = lane >> 4;
  const int prob = blockIdx.x;
  const int p2 = prob % n2, p1 = (prob / n2) % n1, p0 = prob / (n2 * n1);
  const u16* qp = qb + p0*q0 + p1*q1 + p2*q2;
  const u16* kp = kb + p0*k0 + p1*k1 + p2*k2;
  const u16* vp = vb + p0*v0 + p1*v1 + p2*v2;
  u16* op = ob + p0*o0 + p1*o1 + p2*o2;

  const int ta = blockIdx.y;
  const int tb = 15 - ta;
  const int wtile = (wid & 4) ? tb : ta;
  const int wq = wtile * 64 + (wid & 3) * 16;
  const float scale2 = scale * 1.44269504f;

  v8s qf[KD];
  #pragma unroll
  for (int kd = 0; kd < KD; kd++) {
    const int dof = kd*32 + lg*8;
    v8s val = {};
    if (dof < D) val = *(const v8s*)&qp[(long)(wq + lr)*qs + dof];
    qf[kd] = val;
  }

  v4f Of[NSUB] = {};
  float m2 = -1.0e30f, l = 0.f;

  const int kkey = tid / (KD2/8), kd8 = (tid % (KD2/8)) * 8;
  const int vkey = tid / (D/8),  vd8 = (tid % (D/8)) * 8;
  v8s kreg = {}, vreg = {};

  if (tid < KCH) { v8s t = {}; if (kd8 < D) t = *(const v8s*)&kp[(long)kkey*ks + kd8]; kreg = t; }
  if (tid < VCH) vreg = *(const v8s*)&vp[(long)vkey*vs + vd8];
  if (tid < KCH) *(v8s*)&Ks[0][kkey*LDK + kd8] = kreg;
  if (tid < VCH) {
    #pragma unroll
    for (int j = 0; j < 8; j++) Vs[0][(vd8+j)*LDV + vkey] = vreg[j];
  }
  __syncthreads();

  for (int c = 0; c <= tb; c++) {
    const int cur = c & 1, nxt = cur ^ 1;
    if (c < tb) {
      const int kc2 = (c + 1) * 64;
      if (tid < KCH) { v8s t = {}; if (kd8 < D) t = *(const v8s*)&kp[(long)(kc2+kkey)*ks + kd8]; kreg = t; }
      if (tid < VCH) vreg = *(const v8s*)&vp[(long)(kc2+vkey)*vs + vd8];
    }
    if (c <= wtile) {
      const int kc = c * 64;
      v4f sf[4];
      #pragma unroll
      for (int f = 0; f < 4; f++) {
        v4f s = {};
        #pragma unroll
        for (int kd = 0; kd < KD; kd++) {
          const v8s kf = *(const v8s*)&Ks[cur][(f*16 + lr)*LDK + kd*32 + lg*8];
          s = __builtin_amdgcn_mfma_f32_16x16x32_bf16(kf, qf[kd], s, 0, 0, 0);
        }
        sf[f] = s;
      }
      const int qg = wq + lr;
      if (kc + 63 > wq) {
        #pragma unroll
        for (int f = 0; f < 4; f++)
          #pragma unroll
          for (int r = 0; r < 4; r++)
            sf[f][r] = (kc + 16*f + 4*lg + r <= qg) ? sf[f][r] : -3.0e38f;
      }
      float mx0 = fmaxf(fmaxf(sf[0][0], sf[0][1]), fmaxf(sf[0][2], sf[0][3]));
      float mx1 = fmaxf(fmaxf(sf[1][0], sf[1][1]), fmaxf(sf[1][2], sf[1][3]));
      float mx2 = fmaxf(fmaxf(sf[2][0], sf[2][1]), fmaxf(sf[2][2], sf[2][3]));
      float mx3 = fmaxf(fmaxf(sf[3][0], sf[3][1]), fmaxf(sf[3][2], sf[3][3]));
      float mx = fmaxf(fmaxf(mx0, mx1), fmaxf(mx2, mx3));
      mx = fmaxf(mx, __shfl_xor(mx, 16));
      mx = fmaxf(mx, __shfl_xor(mx, 32));
      const float mn2 = fmaxf(m2, mx * scale2);
      const float al = EXP2F(m2 - mn2);
      m2 = mn2;
      float pv[4][4];
      #pragma unroll
      for (int f = 0; f < 4; f++)
        #pragma unroll
        for (int r = 0; r < 4; r++)
          pv[f][r] = EXP2F(__builtin_fmaf(sf[f][r], scale2, -mn2));
      float s0 = (pv[0][0]+pv[0][1]) + (pv[0][2]+pv[0][3]);
      float s1 = (pv[1][0]+pv[1][1]) + (pv[1][2]+pv[1][3]);
      float s2 = (pv[2][0]+pv[2][1]) + (pv[2][2]+pv[2][3]);
      float s3 = (pv[3][0]+pv[3][1]) + (pv[3][2]+pv[3][3]);
      float ps = (s0+s1) + (s2+s3);
      ps += __shfl_xor(ps, 16);
      ps += __shfl_xor(ps, 32);
      l = l * al + ps;
      #pragma unroll
      for (int sub = 0; sub < NSUB; sub++)
        #pragma unroll
        for (int r = 0; r < 4; r++) Of[sub][r] *= al;
      unsigned int pw[8];
      #pragma unroll
      for (int f = 0; f < 4; f++) {
        pw[2*f]   = cvt_pk_bf16(pv[f][0], pv[f][1]);
        pw[2*f+1] = cvt_pk_bf16(pv[f][2], pv[f][3]);
      }
      #pragma unroll
      for (int kb2 = 0; kb2 < 2; kb2++) {
        union { unsigned int w[4]; v8s v; } pb;
        pb.w[0] = pw[4*kb2];   pb.w[1] = pw[4*kb2+1];
        pb.w[2] = pw[4*kb2+2]; pb.w[3] = pw[4*kb2+3];
        #pragma unroll
        for (int sub = 0; sub < NSUB; sub++) {
          union { v4s16 h[2]; v8s v; } va;
          const int vbase = (sub*16 + lr)*LDV + kb2*32 + 4*lg;
          va.h[0] = *(const v4s16*)&Vs[cur][vbase];
          va.h[1] = *(const v4s16*)&Vs[cur][vbase + 16];
          Of[sub] = __builtin_amdgcn_mfma_f32_16x16x32_bf16(va.v, pb.v, Of[sub], 0, 0, 0);
        }
      }
    }
    if (c < tb) {
      if (tid < KCH) *(v8s*)&Ks[nxt][kkey*LDK + kd8] = kreg;
      if (tid < VCH) {
        #pragma unroll
        for (int j = 0; j < 8; j++) Vs[nxt][(vd8+j)*LDV + vkey] = vreg[j];
      }
    }
    __syncthreads();
  }
  const float rl = __builtin_amdgcn_rcpf(l);
  #pragma unroll
  for (int sub = 0; sub < NSUB; sub++) {
    unsigned int w0 = cvt_pk_bf16(Of[sub][0]*rl, Of[sub][1]*rl);
    unsigned int w1 = cvt_pk_bf16(Of[sub][2]*rl, Of[sub][3]*rl);
    unsigned int* dst = (unsigned int*)&op[(long)(wq + lr)*os + sub*16 + 4*lg];
    dst[0] = w0; dst[1] = w1;
  }
}

// ---------------- ctx = mean over T of final tiny-layer output ------------------
__global__ __launch_bounds__(256) void ctx_mean_k(const u16* __restrict__ tb, float* __restrict__ ctx)
{
  const int hb = blockIdx.x;              // h*2+b
  const int h = hb >> 1, b = hb & 1;
  const int d = threadIdx.x & 63, chunk = threadIdx.x >> 6;   // 4 T-chunks
  const u16* p = tb + (long)h*2048*64 + (long)b*1024*64 + d;
  float s = 0.f;
  for (int t = chunk*256; t < (chunk+1)*256; t++) s += bf2f(p[(long)t*64]);
  __shared__ float red[4][64];
  red[chunk][d] = s;
  __syncthreads();
  if (threadIdx.x < 64) {
    const float tot = red[0][d] + red[1][d] + red[2][d] + red[3][d];
    ctx[hb*64 + d] = tot * (1.0f/1024.0f);
  }
}

// ---------------- A,B low-rank projections --------------------------------------
__global__ __launch_bounds__(256) void ab_proj_k(const float* __restrict__ ctx,
    const u16* __restrict__ toA, const u16* __restrict__ toB,
    float* __restrict__ Am, float* __restrict__ Bm)
{
  const int hb = blockIdx.x; const int h = hb >> 1;
  const float* c = ctx + hb * 64;
  for (int n = threadIdx.x; n < 512; n += 256) {
    const u16* wa = toA + ((long)h*512 + n) * 64;
    const u16* wb = toB + ((long)h*512 + n) * 64;
    float sa = 0.f, sb = 0.f;
    for (int i = 0; i < 64; i++) { sa += c[i]*bf2f(wa[i]); sb += c[i]*bf2f(wb[i]); }
    Am[hb*512 + n] = sa;   // n = d*8+r
    Bm[hb*512 + n] = sb;   // n = r*64+d
  }
}

// ---------------- v += SCALE * (v @ A) @ B  (rank-8, in place) ------------------
__global__ __launch_bounds__(256) void delta_v_k(
    u16* __restrict__ v, const float* __restrict__ Am, const float* __restrict__ Bm)
{
  const long idx = (long)blockIdx.x * blockDim.x + threadIdx.x;
  const int h = (int)((idx >> 10) & 15);
  const int b = (int)(idx >> 14);
  u16* row = v + idx * 64;
  const float* A = Am + (h*2 + b) * 512;
  const float* B = Bm + (h*2 + b) * 512;
  float tmp[8] = {};
  #pragma unroll 8
  for (int d = 0; d < 64; d++) {
    const float vd = bf2f(row[d]);
    #pragma unroll
    for (int r = 0; r < 8; r++) tmp[r] += vd * A[d*8 + r];
  }
  #pragma unroll 8
  for (int d = 0; d < 64; d++) {
    float s = 0.f;
    #pragma unroll
    for (int r = 0; r < 8; r++) s += tmp[r] * B[r*64 + d];
    row[d] = f2bf(bf2f(row[d]) + 2.0f * s);   // SCALE = 16/8 = 2
  }
}

extern "C" void kernel_launch(void* const* d_in, const int* in_sizes, int n_in,
                              void* d_out, int out_size, void* d_ws, size_t ws_size,
                              hipStream_t stream) {
  (void)in_sizes; (void)n_in; (void)out_size; (void)ws_size;
  float* out = (float*)d_out;

  char* ws = (char*)d_ws;
  size_t off = 0;
  auto alloc = [&](size_t bytes){ void* p = ws + off; off += (bytes + 255) & ~(size_t)255; return p; };

  static const int ns[13] = {2097152, 32768, 32768, 3145728, 3072, 1048576, 1024,
                             393216, 6144, 131072, 2048, 524288, 524288};
  u16* bufs[13];
  for (int i = 0; i < 13; i++) bufs[i] = (u16*)alloc((size_t)ns[i] * 2);
  u16* xb    = bufs[0];
  u16* cosb  = bufs[1];
  u16* sinb  = bufs[2];
  u16* attnw = bufs[3];
  u16* attnb = bufs[4];
  u16* projw = bufs[5];
  u16* projb = bufs[6];
  u16* hinw  = bufs[7];
  u16* hinb  = bufs[8];
  u16* houtw = bufs[9];
  u16* houtb = bufs[10];
  u16* toAb  = bufs[11];
  u16* toBb  = bufs[12];

  u16* qkv  = (u16*)alloc(6291456ull*2);   // (B,T,3C)
  u16* q_r  = (u16*)alloc(2097152ull*2);   // (B,H,T,64)
  u16* k_r  = (u16*)alloc(2097152ull*2);
  u16* v    = (u16*)alloc(2097152ull*2);
  u16* tqkv = (u16*)alloc(6291456ull*2);   // (H, B*T, 192)
  u16* tatt = (u16*)alloc(2097152ull*2);   // (H, B*T, 64)
  u16* tb0  = (u16*)alloc(2097152ull*2);
  u16* tb1  = (u16*)alloc(2097152ull*2);
  u16* yat  = (u16*)alloc(2097152ull*2);   // (B,T,C)
  float* ctx  = (float*)alloc(2048*4);
  float* Amat = (float*)alloc(16384*4);
  float* Bmat = (float*)alloc(16384*4);

  // 0. convert all inputs fp32 -> bf16
  CvtArgs ca;
  int bacc = 0;
  for (int i = 0; i < 13; i++) {
    ca.s[i] = (const float*)d_in[i];
    ca.d[i] = bufs[i];
    ca.n[i] = ns[i];
    ca.bstart[i] = bacc;
    bacc += (ns[i] + 1023) / 1024;
  }
  ca.bstart[13] = bacc;
  cvt_all<<<dim3(bacc), 256, 0, stream>>>(ca);

  // 1. qkv = x @ c_attn_w^T + b          (2048 x 3072 x 1024), 64x128 tiles
  gemm_nt<64,128,false><<<dim3(24,32,1),256,0,stream>>>(xb,0,1024, attnw,0, attnb,0,
                                                        qkv,0,3072, 1024);
  // 2. rope + split to (B,H,T,64)
  rope_split_k<<<dim3(8192),256,0,stream>>>(qkv, cosb, sinb, q_r, k_r, v);

  // 3. tiny hyper-net: 2 MHA layers over 16 heads
  const u16* tin = xb; long tinBatch = 64; int tinLda = 1024;
  u16* touts[2] = {tb0, tb1};
  for (int l = 0; l < 2; l++) {
    gemm_nt<64,64,false><<<dim3(3,32,16),256,0,stream>>>(tin, tinBatch, tinLda,
        hinw + (size_t)l*192*64, (long)2*192*64,
        hinb + (size_t)l*192,    (long)2*192,
        tqkv, (long)2048*192, 192, 64);
    flash_mfma<16><<<dim3(128,8),512,0,stream>>>(tqkv, tqkv+64, tqkv+128, tatt,
        0.25f, 2, 4,
        (long)2048*192, (long)1024*192, 16L, 192,
        (long)2048*192, (long)1024*192, 16L, 192,
        (long)2048*192, (long)1024*192, 16L, 192,
        (long)2048*64,  (long)1024*64,  16L, 64);
    gemm_nt<64,64,false><<<dim3(1,32,16),256,0,stream>>>(tatt, (long)2048*64, 64,
        houtw + (size_t)l*64*64, (long)2*64*64,
        houtb + (size_t)l*64,    (long)2*64,
        touts[l], (long)2048*64, 64, 64);
    tin = touts[l]; tinBatch = (long)2048*64; tinLda = 64;
  }
  // 4. ctx mean, A/B projections, rank-8 V update
  ctx_mean_k<<<dim3(32),256,0,stream>>>(tb1, ctx);
  ab_proj_k<<<dim3(32),256,0,stream>>>(ctx, toAb, toBb, Amat, Bmat);
  delta_v_k<<<dim3(128),256,0,stream>>>(v, Amat, Bmat);

  // 5. main causal attention (32 problems, D=64)
  flash_mfma<64><<<dim3(32,8),512,0,stream>>>(q_r, k_r, v, yat,
      0.125f, 16, 1,
      (long)16*1024*64, (long)1024*64, 0L, 64,
      (long)16*1024*64, (long)1024*64, 0L, 64,
      (long)16*1024*64, (long)1024*64, 0L, 64,
      (long)1024*1024,  64L,           0L, 1024);

  // 6. out = yat @ c_proj_w^T + b        (2048 x 1024 x 1024), fp32 out, 64x64
  gemm_nt<64,64,true><<<dim3(16,32,1),256,0,stream>>>(yat,0,1024, projw,0, projb,0,
                                                      out,0,1024, 1024);
}

// Round 8
// 274.800 us; speedup vs baseline: 9.4305x; 1.0166x over previous
//
#include <hip/hip_runtime.h>

typedef unsigned short u16;
typedef short v8s __attribute__((ext_vector_type(8)));
typedef short v4s16 __attribute__((ext_vector_type(4)));
typedef float v4f __attribute__((ext_vector_type(4)));

#if defined(__has_builtin)
#  if __has_builtin(__builtin_amdgcn_exp2f)
#    define EXP2F(x) __builtin_amdgcn_exp2f(x)
#  else
#    define EXP2F(x) exp2f(x)
#  endif
#else
#  define EXP2F(x) exp2f(x)
#endif

__device__ __forceinline__ float bf2f(u16 u){
  union { float f; unsigned int i; } c; c.i = ((unsigned int)u) << 16; return c.f;
}
__device__ __forceinline__ u16 f2bf(float f){
  union { float f; unsigned int i; } c; c.f = f;
  unsigned int r = c.i + 0x7FFFu + ((c.i >> 16) & 1u);
  return (u16)(r >> 16);
}
__device__ __forceinline__ unsigned int cvt_pk_bf16(float lo, float hi){
  unsigned int r;
  asm("v_cvt_pk_bf16_f32 %0, %1, %2" : "=v"(r) : "v"(lo), "v"(hi));
  return r;
}

// ---------------- fp32 -> bf16 conversion of all inputs + ctx zero --------------
struct CvtArgs {
  const float* s[13];
  u16* d[13];
  int n[13];
  int bstart[14];
  float* ctxz;
};
__global__ __launch_bounds__(256) void cvt_all(CvtArgs a) {
  if ((int)blockIdx.x >= a.bstart[13]) {      // last block: zero ctx (2048 floats)
    float4 z = {0.f, 0.f, 0.f, 0.f};
    ((float4*)a.ctxz)[threadIdx.x] = z;
    ((float4*)a.ctxz)[256 + threadIdx.x] = z;
    return;
  }
  int j = 0;
  #pragma unroll
  for (int i = 1; i < 13; i++) if ((int)blockIdx.x >= a.bstart[i]) j = i;
  const int lb = blockIdx.x - a.bstart[j];
  const long base = (long)lb * 1024 + threadIdx.x * 4;
  if (base < a.n[j]) {
    const float4 f = *(const float4*)&a.s[j][base];
    v4s16 o;
    o.x = (short)f2bf(f.x); o.y = (short)f2bf(f.y);
    o.z = (short)f2bf(f.z); o.w = (short)f2bf(f.w);
    *(v4s16*)&a.d[j][base] = o;
  }
}

// ---------------- batched GEMM: C[g][M,N] = A[g][M,K] @ W[g][N,K]^T + bias[g] ----
// 2-phase prefetch (issue-early/write-late). Epilogues:
//   EPI=0: bf16 C   EPI=1: fp32 C
//   EPI=2: fused RoPE + (B,H,T,D) split of qkv (writes q_r/k_r/v_out)
//   EPI=3: fused ctx mean (atomicAdd column sums / 1024; no C write)
template<int BM, int BN, int EPI>
__global__ __launch_bounds__(256) void gemm_nt(
    const u16* __restrict__ A, long aBatch, int lda,
    const u16* __restrict__ W, long wBatch,
    const u16* __restrict__ bias, long bBatch,
    void* __restrict__ Cp, long cBatch, int ldc,
    int K,
    const u16* __restrict__ cosb, const u16* __restrict__ sinb,
    u16* __restrict__ q_r, u16* __restrict__ k_r, u16* __restrict__ v_out,
    float* __restrict__ ctxp)
{
  constexpr int BK = 64, LDT = BK + 8;
  constexpr int AC = BM / 32;
  constexpr int BC = BN / 32;
  A    += (long)blockIdx.z * aBatch;
  W    += (long)blockIdx.z * wBatch;
  bias += (long)blockIdx.z * bBatch;
  const int row0 = blockIdx.y * BM, col0 = blockIdx.x * BN;
  __shared__ __align__(16) u16 As[BM * LDT];
  __shared__ __align__(16) u16 Bs[BN * LDT];
  const int tid = threadIdx.x, wid = tid >> 6, lane = tid & 63;
  constexpr int FM = (BM/2)/16, FN = (BN/2)/16;
  const int wr = (wid >> 1) * (BM/2), wc = (wid & 1) * (BN/2);
  v4f acc[FM][FN] = {};
  const int lr = lane & 15, lk = (lane >> 4) * 8;

  v8s areg[AC], breg[BC];
  auto loadAB = [&](int k0) {
    #pragma unroll
    for (int i = 0; i < AC; i++) {
      const int c = tid + i*256, r = c >> 3, cc = (c & 7) * 8;
      areg[i] = *(const v8s*)&A[(long)(row0 + r)*lda + k0 + cc];
    }
    #pragma unroll
    for (int i = 0; i < BC; i++) {
      const int c = tid + i*256, r = c >> 3, cc = (c & 7) * 8;
      breg[i] = *(const v8s*)&W[(long)(col0 + r)*K + k0 + cc];
    }
  };
  auto writeAB = [&]() {
    #pragma unroll
    for (int i = 0; i < AC; i++) {
      const int c = tid + i*256, r = c >> 3, cc = (c & 7) * 8;
      *(v8s*)&As[r*LDT + cc] = areg[i];
    }
    #pragma unroll
    for (int i = 0; i < BC; i++) {
      const int c = tid + i*256, r = c >> 3, cc = (c & 7) * 8;
      *(v8s*)&Bs[r*LDT + cc] = breg[i];
    }
  };

  loadAB(0); writeAB();
  __syncthreads();
  for (int k0 = 0; k0 < K; k0 += BK) {
    if (k0 + BK < K) loadAB(k0 + BK);
    #pragma unroll
    for (int ks = 0; ks < BK; ks += 32) {
      v8s af[FM], bfv[FN];
      #pragma unroll
      for (int i = 0; i < FM; i++) af[i]  = *(const v8s*)&As[(wr + i*16 + lr)*LDT + ks + lk];
      #pragma unroll
      for (int j = 0; j < FN; j++) bfv[j] = *(const v8s*)&Bs[(wc + j*16 + lr)*LDT + ks + lk];
      #pragma unroll
      for (int i = 0; i < FM; i++)
        #pragma unroll
        for (int j = 0; j < FN; j++)
          acc[i][j] = __builtin_amdgcn_mfma_f32_16x16x32_bf16(af[i], bfv[j], acc[i][j], 0, 0, 0);
    }
    __syncthreads();
    if (k0 + BK < K) {
      writeAB();
      __syncthreads();
    }
  }
  const int lc = lane & 15, lq = (lane >> 4) * 4;
  if (EPI <= 1) {
    u16*   Cb = (u16*)Cp   + (long)blockIdx.z * cBatch;
    float* Cf = (float*)Cp + (long)blockIdx.z * cBatch;
    #pragma unroll
    for (int i = 0; i < FM; i++)
      #pragma unroll
      for (int j = 0; j < FN; j++) {
        const int cidx = col0 + wc + j*16 + lc;
        const float bv = bf2f(bias[cidx]);
        #pragma unroll
        for (int q = 0; q < 4; q++) {
          const int r = row0 + wr + i*16 + lq + q;
          if (EPI == 1) Cf[(long)r*ldc + cidx] = acc[i][j][q] + bv;
          else          Cb[(long)r*ldc + cidx] = f2bf(acc[i][j][q] + bv);
        }
      }
  } else if (EPI == 2) {
    // rope + split: cidx -> (which, head, d); rows -> (b, t)
    #pragma unroll
    for (int i = 0; i < FM; i++)
      #pragma unroll
      for (int j = 0; j < FN; j++) {
        const int cidx = col0 + wc + j*16 + lc;
        const float bv = bf2f(bias[cidx]);
        const int which = cidx >> 10;            // uniform per (i,j)
        const int h = (cidx & 1023) >> 6;
        const int d = cidx & 63;
        u16* dst = (which == 0) ? q_r : (which == 1) ? k_r : v_out;
        #pragma unroll
        for (int q = 0; q < 4; q++) {
          const int r = row0 + wr + i*16 + lq + q;
          const int b = r >> 10, t = r & 1023;
          float val = acc[i][j][q] + bv;
          float par = __shfl_xor(val, 1);        // partner d (d^1)
          float outv;
          if (which == 2) {
            outv = val;
          } else {
            const int i2 = d >> 1;
            const float cc = bf2f(cosb[(t << 5) + i2]);
            const float ss = bf2f(sinb[(t << 5) + i2]);
            outv = (d & 1) ? __builtin_fmaf(par, ss,  val*cc)
                           : __builtin_fmaf(val, cc, -par*ss);
          }
          dst[((long)((b << 4) + h)*1024 + t)*64 + d] = f2bf(outv);
        }
      }
  } else {  // EPI == 3: column-mean accumulation into ctx
    const float inv = 1.0f/1024.0f;
    const int hb = (blockIdx.z << 1) + (row0 >> 10);
    #pragma unroll
    for (int j = 0; j < FN; j++) {
      const int cidx = col0 + wc + j*16 + lc;
      const float bv = bf2f(bias[cidx]);
      float p = (float)(FM*4) * bv;
      #pragma unroll
      for (int i = 0; i < FM; i++)
        #pragma unroll
        for (int q = 0; q < 4; q++) p += acc[i][j][q];
      p += __shfl_xor(p, 16);
      p += __shfl_xor(p, 32);
      if (lane < 16) atomicAdd(&ctxp[hb*64 + cidx], p * inv);
    }
  }
}

// ---------------- MFMA flash attention v4 (KBLK=128, swapped layout) -------------
// 512 threads / 8 waves. Paired q-tiles ta / 15-ta (uniform 9 chunks/block).
// Swapped QK^T (S^T per-lane), in-register softmax (2 shfl), zero-shuffle PV
// via k-permutation, double-buffered K/V with issue-early/write-late staging.
template<int D>
__global__ __launch_bounds__(512) void flash_mfma(
    const u16* __restrict__ qb, const u16* __restrict__ kb,
    const u16* __restrict__ vb, u16* __restrict__ ob,
    float scale, int n1, int n2,
    long q0, long q1, long q2, int qs,
    long k0, long k1, long k2, int ks,
    long v0, long v1, long v2, int vs,
    long o0, long o1, long o2, int os)
{
  constexpr int KBLK = 128;
  constexpr int NF  = KBLK / 16;           // 8 score frags
  constexpr int NKB = KBLK / 32;           // 4 PV k-steps
  constexpr int KD2 = (D < 32) ? 32 : D;
  constexpr int LDK = KD2 + 8;
  constexpr int LDV = KBLK + 8;
  constexpr int KD  = KD2 / 32;
  constexpr int NSUB = D / 16;
  constexpr int KCH = KBLK * (KD2/8);      // 512 (D16) / 1024 (D64)
  constexpr int VCH = (D/8) * KBLK;        // 256 / 1024
  constexpr int KIT = (KCH + 511) / 512;
  constexpr int VIT = (VCH + 511) / 512;
  __shared__ __align__(16) u16 Ks[2][KBLK * LDK];
  __shared__ __align__(16) u16 Vs[2][D * LDV];

  const int tid = threadIdx.x, wid = tid >> 6, lane = tid & 63;
  const int lr = lane & 15, lg = lane >> 4;
  const int prob = blockIdx.x;
  const int p2 = prob % n2, p1 = (prob / n2) % n1, p0 = prob / (n2 * n1);
  const u16* qp = qb + p0*q0 + p1*q1 + p2*q2;
  const u16* kp = kb + p0*k0 + p1*k1 + p2*k2;
  const u16* vp = vb + p0*v0 + p1*v1 + p2*v2;
  u16* op = ob + p0*o0 + p1*o1 + p2*o2;

  const int ta = blockIdx.y;               // 0..7
  const int tbt = 15 - ta;                 // 8..15
  const int wtile = (wid & 4) ? tbt : ta;
  const int wq = wtile * 64 + (wid & 3) * 16;
  const int nchb = (tbt >> 1) + 1;         // chunks for the deeper tile
  const float scale2 = scale * 1.44269504f;

  v8s qf[KD];
  #pragma unroll
  for (int kd = 0; kd < KD; kd++) {
    const int dof = kd*32 + lg*8;
    v8s val = {};
    if (dof < D) val = *(const v8s*)&qp[(long)(wq + lr)*qs + dof];
    qf[kd] = val;
  }

  v4f Of[NSUB] = {};
  float m2 = -1.0e30f, l = 0.f;

  v8s kreg[KIT], vreg[VIT];
  auto loadK = [&](int kc) {
    #pragma unroll
    for (int i = 0; i < KIT; i++) {
      const int idx = tid + i*512;
      if (idx < KCH) {
        const int key = idx / (KD2/8), d8 = (idx % (KD2/8)) * 8;
        v8s t = {};
        if (d8 < D) t = *(const v8s*)&kp[(long)(kc + key)*ks + d8];
        kreg[i] = t;
      }
    }
  };
  auto loadV = [&](int kc) {
    #pragma unroll
    for (int i = 0; i < VIT; i++) {
      const int idx = tid + i*512;
      if (idx < VCH) {
        const int key = idx / (D/8), d8 = (idx % (D/8)) * 8;
        vreg[i] = *(const v8s*)&vp[(long)(kc + key)*vs + d8];
      }
    }
  };
  auto writeKV = [&](int buf) {
    #pragma unroll
    for (int i = 0; i < KIT; i++) {
      const int idx = tid + i*512;
      if (idx < KCH) {
        const int key = idx / (KD2/8), d8 = (idx % (KD2/8)) * 8;
        *(v8s*)&Ks[buf][key*LDK + d8] = kreg[i];
      }
    }
    #pragma unroll
    for (int i = 0; i < VIT; i++) {
      const int idx = tid + i*512;
      if (idx < VCH) {
        const int key = idx / (D/8), d8 = (idx % (D/8)) * 8;
        #pragma unroll
        for (int j = 0; j < 8; j++) Vs[buf][(d8+j)*LDV + key] = vreg[i][j];
      }
    }
  };

  loadK(0); loadV(0); writeKV(0);
  __syncthreads();

  for (int c = 0; c < nchb; c++) {
    const int cur = c & 1, nxt = cur ^ 1;
    if (c + 1 < nchb) { loadK((c+1)*KBLK); loadV((c+1)*KBLK); }
    const int kc = c * KBLK;
    if (kc <= wq + 15) {
      // ---- S^T frags: sf[f][r] = S[key=kc+16f+4lg+r][q=wq+lr] ----
      v4f sf[NF];
      #pragma unroll
      for (int f = 0; f < NF; f++) {
        v4f s = {};
        #pragma unroll
        for (int kd = 0; kd < KD; kd++) {
          const v8s kf = *(const v8s*)&Ks[cur][(f*16 + lr)*LDK + kd*32 + lg*8];
          s = __builtin_amdgcn_mfma_f32_16x16x32_bf16(kf, qf[kd], s, 0, 0, 0);
        }
        sf[f] = s;
      }
      const int qg = wq + lr;
      if (kc + KBLK - 1 > wq) {
        #pragma unroll
        for (int f = 0; f < NF; f++)
          #pragma unroll
          for (int r = 0; r < 4; r++)
            sf[f][r] = (kc + 16*f + 4*lg + r <= qg) ? sf[f][r] : -3.0e38f;
      }
      // ---- in-register softmax over 32 keys + 2 shfl ----
      float mx = -3.0e38f;
      #pragma unroll
      for (int f = 0; f < NF; f++)
        mx = fmaxf(mx, fmaxf(fmaxf(sf[f][0], sf[f][1]), fmaxf(sf[f][2], sf[f][3])));
      mx = fmaxf(mx, __shfl_xor(mx, 16));
      mx = fmaxf(mx, __shfl_xor(mx, 32));
      const float mn2 = fmaxf(m2, mx * scale2);
      const float al = EXP2F(m2 - mn2);
      m2 = mn2;
      float pv[NF][4];
      float ps = 0.f;
      #pragma unroll
      for (int f = 0; f < NF; f++) {
        #pragma unroll
        for (int r = 0; r < 4; r++)
          pv[f][r] = EXP2F(__builtin_fmaf(sf[f][r], scale2, -mn2));
        ps += (pv[f][0] + pv[f][1]) + (pv[f][2] + pv[f][3]);
      }
      ps += __shfl_xor(ps, 16);
      ps += __shfl_xor(ps, 32);
      l = l * al + ps;
      #pragma unroll
      for (int sub = 0; sub < NSUB; sub++)
        #pragma unroll
        for (int r = 0; r < 4; r++) Of[sub][r] *= al;
      // ---- pack P (lane-resident) ----
      unsigned int pw[2*NF];
      #pragma unroll
      for (int f = 0; f < NF; f++) {
        pw[2*f]   = cvt_pk_bf16(pv[f][0], pv[f][1]);
        pw[2*f+1] = cvt_pk_bf16(pv[f][2], pv[f][3]);
      }
      // ---- PV with k-perm key(kb2,lg,j)=kb2*32+16*(j>>2)+4lg+(j&3) ----
      #pragma unroll
      for (int kb2 = 0; kb2 < NKB; kb2++) {
        union { unsigned int w[4]; v8s v; } pb;
        pb.w[0] = pw[4*kb2];   pb.w[1] = pw[4*kb2+1];
        pb.w[2] = pw[4*kb2+2]; pb.w[3] = pw[4*kb2+3];
        #pragma unroll
        for (int sub = 0; sub < NSUB; sub++) {
          union { v4s16 h[2]; v8s v; } va;
          const int vbase = (sub*16 + lr)*LDV + kb2*32 + 4*lg;
          va.h[0] = *(const v4s16*)&Vs[cur][vbase];
          va.h[1] = *(const v4s16*)&Vs[cur][vbase + 16];
          Of[sub] = __builtin_amdgcn_mfma_f32_16x16x32_bf16(va.v, pb.v, Of[sub], 0, 0, 0);
        }
      }
    }
    if (c + 1 < nchb) writeKV(nxt);
    __syncthreads();
  }
  const float rl = __builtin_amdgcn_rcpf(l);
  #pragma unroll
  for (int sub = 0; sub < NSUB; sub++) {
    unsigned int w0 = cvt_pk_bf16(Of[sub][0]*rl, Of[sub][1]*rl);
    unsigned int w1 = cvt_pk_bf16(Of[sub][2]*rl, Of[sub][3]*rl);
    unsigned int* dst = (unsigned int*)&op[(long)(wq + lr)*os + sub*16 + 4*lg];
    dst[0] = w0; dst[1] = w1;
  }
}

// ---------------- A,B low-rank projections --------------------------------------
__global__ __launch_bounds__(256) void ab_proj_k(const float* __restrict__ ctx,
    const u16* __restrict__ toA, const u16* __restrict__ toB,
    float* __restrict__ Am, float* __restrict__ Bm)
{
  const int hb = blockIdx.x; const int h = hb >> 1;
  const float* c = ctx + hb * 64;
  for (int n = threadIdx.x; n < 512; n += 256) {
    const u16* wa = toA + ((long)h*512 + n) * 64;
    const u16* wb = toB + ((long)h*512 + n) * 64;
    float sa = 0.f, sb = 0.f;
    for (int i = 0; i < 64; i++) { sa += c[i]*bf2f(wa[i]); sb += c[i]*bf2f(wb[i]); }
    Am[hb*512 + n] = sa;   // n = d*8+r
    Bm[hb*512 + n] = sb;   // n = r*64+d
  }
}

// ---------------- v += SCALE * (v @ A) @ B  (rank-8, in place) ------------------
__global__ __launch_bounds__(256) void delta_v_k(
    u16* __restrict__ v, const float* __restrict__ Am, const float* __restrict__ Bm)
{
  const long idx = (long)blockIdx.x * blockDim.x + threadIdx.x;
  const int h = (int)((idx >> 10) & 15);
  const int b = (int)(idx >> 14);
  u16* row = v + idx * 64;
  const float* A = Am + (h*2 + b) * 512;
  const float* B = Bm + (h*2 + b) * 512;
  float tmp[8] = {};
  #pragma unroll 8
  for (int d = 0; d < 64; d++) {
    const float vd = bf2f(row[d]);
    #pragma unroll
    for (int r = 0; r < 8; r++) tmp[r] += vd * A[d*8 + r];
  }
  #pragma unroll 8
  for (int d = 0; d < 64; d++) {
    float s = 0.f;
    #pragma unroll
    for (int r = 0; r < 8; r++) s += tmp[r] * B[r*64 + d];
    row[d] = f2bf(bf2f(row[d]) + 2.0f * s);   // SCALE = 16/8 = 2
  }
}

extern "C" void kernel_launch(void* const* d_in, const int* in_sizes, int n_in,
                              void* d_out, int out_size, void* d_ws, size_t ws_size,
                              hipStream_t stream) {
  (void)in_sizes; (void)n_in; (void)out_size; (void)ws_size;
  float* out = (float*)d_out;

  char* ws = (char*)d_ws;
  size_t off = 0;
  auto alloc = [&](size_t bytes){ void* p = ws + off; off += (bytes + 255) & ~(size_t)255; return p; };

  static const int ns[13] = {2097152, 32768, 32768, 3145728, 3072, 1048576, 1024,
                             393216, 6144, 131072, 2048, 524288, 524288};
  u16* bufs[13];
  for (int i = 0; i < 13; i++) bufs[i] = (u16*)alloc((size_t)ns[i] * 2);
  u16* xb    = bufs[0];
  u16* cosb  = bufs[1];
  u16* sinb  = bufs[2];
  u16* attnw = bufs[3];
  u16* attnb = bufs[4];
  u16* projw = bufs[5];
  u16* projb = bufs[6];
  u16* hinw  = bufs[7];
  u16* hinb  = bufs[8];
  u16* houtw = bufs[9];
  u16* houtb = bufs[10];
  u16* toAb  = bufs[11];
  u16* toBb  = bufs[12];

  u16* q_r  = (u16*)alloc(2097152ull*2);   // (B,H,T,64)
  u16* k_r  = (u16*)alloc(2097152ull*2);
  u16* v    = (u16*)alloc(2097152ull*2);
  u16* tqkv = (u16*)alloc(6291456ull*2);   // (H, B*T, 192)
  u16* tatt = (u16*)alloc(2097152ull*2);   // (H, B*T, 64)
  u16* tb0  = (u16*)alloc(2097152ull*2);
  u16* yat  = (u16*)alloc(2097152ull*2);   // (B,T,C)
  float* ctx  = (float*)alloc(2048*4);
  float* Amat = (float*)alloc(16384*4);
  float* Bmat = (float*)alloc(16384*4);

  // 0. convert all inputs fp32 -> bf16 (+ zero ctx in the extra block)
  CvtArgs ca;
  int bacc = 0;
  for (int i = 0; i < 13; i++) {
    ca.s[i] = (const float*)d_in[i];
    ca.d[i] = bufs[i];
    ca.n[i] = ns[i];
    ca.bstart[i] = bacc;
    bacc += (ns[i] + 1023) / 1024;
  }
  ca.bstart[13] = bacc;
  ca.ctxz = ctx;
  cvt_all<<<dim3(bacc + 1), 256, 0, stream>>>(ca);

  // 1. qkv = x @ c_attn_w^T + b, fused RoPE + (B,H,T,64) split
  gemm_nt<64,64,2><<<dim3(48,32,1),256,0,stream>>>(xb,0,1024, attnw,0, attnb,0,
      nullptr,0,0, 1024, cosb, sinb, q_r, k_r, v, nullptr);

  // 2. tiny hyper-net: 2 MHA layers over 16 heads
  // layer 0
  gemm_nt<64,64,0><<<dim3(3,32,16),256,0,stream>>>(xb, 64L, 1024,
      hinw, (long)2*192*64, hinb, (long)2*192,
      tqkv, (long)2048*192, 192, 64,
      nullptr, nullptr, nullptr, nullptr, nullptr, nullptr);
  flash_mfma<16><<<dim3(128,8),512,0,stream>>>(tqkv, tqkv+64, tqkv+128, tatt,
      0.25f, 2, 4,
      (long)2048*192, (long)1024*192, 16L, 192,
      (long)2048*192, (long)1024*192, 16L, 192,
      (long)2048*192, (long)1024*192, 16L, 192,
      (long)2048*64,  (long)1024*64,  16L, 64);
  gemm_nt<64,64,0><<<dim3(1,32,16),256,0,stream>>>(tatt, (long)2048*64, 64,
      houtw, (long)2*64*64, houtb, (long)2*64,
      tb0, (long)2048*64, 64, 64,
      nullptr, nullptr, nullptr, nullptr, nullptr, nullptr);
  // layer 1 (out-gemm fused into ctx mean)
  gemm_nt<64,64,0><<<dim3(3,32,16),256,0,stream>>>(tb0, (long)2048*64, 64,
      hinw + (size_t)192*64, (long)2*192*64, hinb + 192, (long)2*192,
      tqkv, (long)2048*192, 192, 64,
      nullptr, nullptr, nullptr, nullptr, nullptr, nullptr);
  flash_mfma<16><<<dim3(128,8),512,0,stream>>>(tqkv, tqkv+64, tqkv+128, tatt,
      0.25f, 2, 4,
      (long)2048*192, (long)1024*192, 16L, 192,
      (long)2048*192, (long)1024*192, 16L, 192,
      (long)2048*192, (long)1024*192, 16L, 192,
      (long)2048*64,  (long)1024*64,  16L, 64);
  gemm_nt<64,64,3><<<dim3(1,32,16),256,0,stream>>>(tatt, (long)2048*64, 64,
      houtw + (size_t)64*64, (long)2*64*64, houtb + 64, (long)2*64,
      nullptr, 0, 0, 64,
      nullptr, nullptr, nullptr, nullptr, nullptr, ctx);

  // 3. A/B projections, rank-8 V update
  ab_proj_k<<<dim3(32),256,0,stream>>>(ctx, toAb, toBb, Amat, Bmat);
  delta_v_k<<<dim3(128),256,0,stream>>>(v, Amat, Bmat);

  // 4. main causal attention (32 problems, D=64)
  flash_mfma<64><<<dim3(32,8),512,0,stream>>>(q_r, k_r, v, yat,
      0.125f, 16, 1,
      (long)16*1024*64, (long)1024*64, 0L, 64,
      (long)16*1024*64, (long)1024*64, 0L, 64,
      (long)16*1024*64, (long)1024*64, 0L, 64,
      (long)1024*1024,  64L,           0L, 1024);

  // 5. out = yat @ c_proj_w^T + b (fp32 out)
  gemm_nt<64,64,1><<<dim3(16,32,1),256,0,stream>>>(yat,0,1024, projw,0, projb,0,
      out,0,1024, 1024,
      nullptr, nullptr, nullptr, nullptr, nullptr, nullptr);
}